// Round 1
// 293.298 us; speedup vs baseline: 1.1699x; 1.1699x over previous
//
#include <hip/hip_runtime.h>
#include <math.h>

// Problem: B=8, L=1024, C=768, nH=12, hd=64, qkv dim 2304. fp32 in, fp32 out.
#define NB 8
#define SL 1024
#define CD 768
#define NHH 12
#define HD 64
#define QKVD 2304

typedef __attribute__((ext_vector_type(8))) __bf16 bf16x8;
typedef __attribute__((ext_vector_type(8))) unsigned short u16x8;
typedef __attribute__((ext_vector_type(4))) float f32x4;
#define MFMA16(a, b, c) __builtin_amdgcn_mfma_f32_16x16x32_bf16(a, b, c, 0, 0, 0)

__host__ __device__ __forceinline__ float bf2f(unsigned short u) {
  union { unsigned int i; float f; } v; v.i = ((unsigned int)u) << 16; return v.f;
}
__host__ __device__ __forceinline__ unsigned short f2bf(float f) {
  union { float ff; unsigned int i; } v; v.ff = f;
  unsigned int x = v.i;
  x += 0x7FFFu + ((x >> 16) & 1u);  // RNE
  return (unsigned short)(x >> 16);
}

// async global->LDS, 16B per lane. LDS dest must be linear in lane order.
__device__ __forceinline__ void gload_lds16(const void* g, void* l) {
  __builtin_amdgcn_global_load_lds(
      (const __attribute__((address_space(1))) unsigned int*)g,
      (__attribute__((address_space(3))) unsigned int*)l, 16, 0, 0);
}

// fp32 -> bf16 bulk convert (memory-bound).
__global__ __launch_bounds__(256) void conv_kernel(
    const float4* __restrict__ in, ushort4* __restrict__ out, int n4)
{
  int i = blockIdx.x * 256 + threadIdx.x;
  if (i < n4) {
    float4 v = in[i];
    ushort4 o;
    o.x = f2bf(v.x); o.y = f2bf(v.y); o.z = f2bf(v.z); o.w = f2bf(v.w);
    out[i] = o;
  }
}

// C[M,N] = A[M,K] @ B[N,K]^T, A,B bf16. CF32: store fp32 else bf16.
// 128x128 tile, BK=32, 256 threads = 4 waves in 2x2 grid, each wave 64x64
// via 4x4 grid of 16x16x32 MFMA. m97 structure: global_load_lds width-16
// staging into LINEAR LDS (no pad; global_load_lds needs contiguous dest).
template <int CF32>
__global__ __launch_bounds__(256) void gemm_mfma(
    const unsigned short* __restrict__ A, const unsigned short* __restrict__ B,
    void* __restrict__ Cv, int M, int N, int K)
{
  __shared__ alignas(16) unsigned short AsL[128 * 32];
  __shared__ alignas(16) unsigned short BsL[128 * 32];
  const int m0 = blockIdx.y * 128, n0 = blockIdx.x * 128;
  const int t = threadIdx.x;
  const int wave = t >> 6, lane = t & 63;
  const int wm = (wave >> 1) * 64, wn = (wave & 1) * 64;
  const int lm = lane & 15, quad = lane >> 4;
  const int sr = t >> 2, sc = (t & 3) * 8;  // staging: row (64 rows/call), col
  f32x4 acc[4][4];
#pragma unroll
  for (int i = 0; i < 4; ++i)
#pragma unroll
    for (int j = 0; j < 4; ++j)
#pragma unroll
      for (int r = 0; r < 4; ++r) acc[i][j][r] = 0.f;

  const unsigned short* ag = A + (size_t)(m0 + sr) * K + sc;
  const unsigned short* bg = B + (size_t)(n0 + sr) * K + sc;
  for (int k0 = 0; k0 < K; k0 += 32) {
    // 4KB per call (256 lanes x 16B); lane t -> LDS offset t*16 (linear).
    gload_lds16(ag + k0, &AsL[t * 8]);
    gload_lds16(ag + (size_t)64 * K + k0, &AsL[2048 + t * 8]);
    gload_lds16(bg + k0, &BsL[t * 8]);
    gload_lds16(bg + (size_t)64 * K + k0, &BsL[2048 + t * 8]);
    __syncthreads();  // drains vmcnt -> LDS staged
    bf16x8 af[4], bfr[4];
#pragma unroll
    for (int i = 0; i < 4; ++i)
      af[i] = *(const bf16x8*)&AsL[(wm + i * 16 + lm) * 32 + quad * 8];
#pragma unroll
    for (int j = 0; j < 4; ++j)
      bfr[j] = *(const bf16x8*)&BsL[(wn + j * 16 + lm) * 32 + quad * 8];
#pragma unroll
    for (int i = 0; i < 4; ++i)
#pragma unroll
      for (int j = 0; j < 4; ++j)
        acc[i][j] = MFMA16(af[i], bfr[j], acc[i][j]);
    __syncthreads();
  }
#pragma unroll
  for (int i = 0; i < 4; ++i) {
    const int row = m0 + wm + i * 16 + quad * 4;
#pragma unroll
    for (int r = 0; r < 4; ++r) {
      const size_t base = (size_t)(row + r) * N + n0 + wn + lm;
#pragma unroll
      for (int j = 0; j < 4; ++j) {
        if (CF32) ((float*)Cv)[base + j * 16] = acc[i][j][r];
        else ((unsigned short*)Cv)[base + j * 16] = f2bf(acc[i][j][r]);
      }
    }
  }
}

// RMSNorm(hd=64) + RoPE in place on q(s=0), k(s=1) planes of bf16 qkv ws.
// One 64-lane wave per (b,l,s,h) vector. Gammas fp32.
__global__ __launch_bounds__(256) void rmsrope_kernel(
    unsigned short* __restrict__ qkv,
    const float* __restrict__ qg, const float* __restrict__ kg)
{
  const int wid  = (int)((blockIdx.x * blockDim.x + threadIdx.x) >> 6);
  const int lane = threadIdx.x & 63;
  const int h = wid % NHH;
  const int s = (wid / NHH) & 1;
  const int l = (wid / (2 * NHH)) % SL;
  const int b = wid / (2 * NHH * SL);
  unsigned short* p = qkv + (((size_t)(b * SL + l) * 3 + s) * NHH + h) * HD + lane;
  float v = bf2f(*p);
  float ss = v * v;
#pragma unroll
  for (int off = 32; off; off >>= 1) ss += __shfl_xor(ss, off);
  float g = s ? kg[lane] : qg[lane];
  v = v * rsqrtf(ss * (1.0f / 64.0f) + 1e-6f) * g;
  float partner = __shfl_xor(v, 32);
  const int j = lane & 31;
  float ang = (float)l * exp2f((float)j * (-13.287712379549449f / 32.0f));
  float sn, cs;
  sincosf(ang, &sn, &cs);
  *p = f2bf((lane < 32) ? (v * cs - partner * sn) : (partner * sn + v * cs));
}

// MFMA flash attention. Block = (qtile 64, head, batch), 256 thr = 4 waves.
// Wave w owns q-rows [w*16, w*16+16) x all 64 keys/dims.
// v2 changes vs v1:
//  - XCD-aware block swizzle: consecutive 192-block chunks (12 full (b,h)
//    groups, KV ~3MB) pinned per XCD -> K/V become L2 hits (was 24.6MB/XCD).
//  - K staged ONCE per block into LDS with coalesced 128B-row loads (was:
//    each of 4 waves re-loading the same K tile from global, 64B scattered).
//  - Still 2 barriers/iter: Ps is written+read by the same wave only, so the
//    post-stage barrier covers everything.
__global__ __launch_bounds__(256) void attn_mfma(
    const unsigned short* __restrict__ qkv, unsigned short* __restrict__ ctx)
{
  __shared__ alignas(16) unsigned short Ks[64][72];  // [key][d], row 144B
  __shared__ alignas(16) unsigned short Vt[64][72];  // [d][key]
  __shared__ alignas(16) unsigned short Ps[64][72];  // [qrow][key]
  // XCD swizzle: grid (16,12,8) x-major linear; XCD = bid & 7 (round-robin).
  const int bid = (int)(blockIdx.x + 16 * (blockIdx.y + 12 * blockIdx.z));
  const int nb = (bid & 7) * 192 + (bid >> 3);  // bijective: 1536 = 8*192
  const int qt = nb & 15;
  const int h = (nb >> 4) % 12;
  const int b = nb / 192;
  const int t = threadIdx.x, wave = t >> 6, lane = t & 63;
  const int lm = lane & 15, quad = lane >> 4;
  const int wq = wave * 16;
  const int vkey = t & 63, vds = (t >> 6) * 16;   // V staging assignment
  const int kr = t >> 2, kc = (t & 3) * 16;       // K staging: 4 thr/row

  bf16x8 qf[2];
  {
    const unsigned short* qp =
        qkv + (((size_t)(b * SL + qt * 64 + wq + lm) * 3 + 0) * NHH + h) * HD;
    qf[0] = *(const bf16x8*)(qp + quad * 8);
    qf[1] = *(const bf16x8*)(qp + 32 + quad * 8);
  }
  f32x4 o[4];
  float m_i[4], l_i[4];
#pragma unroll
  for (int j = 0; j < 4; ++j) {
    m_i[j] = -INFINITY; l_i[j] = 0.f;
#pragma unroll
    for (int r = 0; r < 4; ++r) o[j][r] = 0.f;
  }

  for (int kt = 0; kt < 16; ++kt) {
    // stage K rows coalesced: thread t covers 32B of key row kr
    {
      const unsigned short* kp =
          qkv + (((size_t)(b * SL + kt * 64 + kr) * 3 + 1) * NHH + h) * HD + kc;
      u16x8 ka = *(const u16x8*)(kp);
      u16x8 kb = *(const u16x8*)(kp + 8);
      *(u16x8*)&Ks[kr][kc] = ka;
      *(u16x8*)&Ks[kr][kc + 8] = kb;
    }
    // stage V transposed: thread t loads V[key=vkey][vds..vds+16)
    {
      const unsigned short* vp =
          qkv + (((size_t)(b * SL + kt * 64 + vkey) * 3 + 2) * NHH + h) * HD + vds;
      u16x8 v0 = *(const u16x8*)(vp);
      u16x8 v1 = *(const u16x8*)(vp + 8);
#pragma unroll
      for (int e = 0; e < 8; ++e) {
        Vt[vds + e][vkey] = v0[e];
        Vt[vds + 8 + e][vkey] = v1[e];
      }
    }
    __syncthreads();  // Ks + Vt staged
    // S = Q K^T (K fragments from LDS)
    f32x4 s[4];
#pragma unroll
    for (int j = 0; j < 4; ++j) {
#pragma unroll
      for (int r = 0; r < 4; ++r) s[j][r] = 0.f;
      bf16x8 k0f = *(const bf16x8*)&Ks[j * 16 + lm][quad * 8];
      bf16x8 k1f = *(const bf16x8*)&Ks[j * 16 + lm][32 + quad * 8];
      s[j] = MFMA16(qf[0], k0f, s[j]);
      s[j] = MFMA16(qf[1], k1f, s[j]);
    }
    // online softmax per row r (rows quad*4+r)
#pragma unroll
    for (int r = 0; r < 4; ++r) {
      float tm = -INFINITY;
#pragma unroll
      for (int j = 0; j < 4; ++j) { s[j][r] *= 0.125f; tm = fmaxf(tm, s[j][r]); }
#pragma unroll
      for (int off = 8; off; off >>= 1) tm = fmaxf(tm, __shfl_xor(tm, off));
      float mn = fmaxf(m_i[r], tm);
      float al = __expf(m_i[r] - mn);
      m_i[r] = mn;
      float rs = 0.f;
#pragma unroll
      for (int j = 0; j < 4; ++j) {
        float p = __expf(s[j][r] - mn);
        rs += p;
        Ps[wq + quad * 4 + r][j * 16 + lm] = f2bf(p);
      }
#pragma unroll
      for (int off = 8; off; off >>= 1) rs += __shfl_xor(rs, off);
      l_i[r] = l_i[r] * al + rs;
#pragma unroll
      for (int j = 0; j < 4; ++j) o[j][r] *= al;
    }
    // No barrier needed: Ps rows [wq,wq+16) are written and read by THIS
    // wave only (in-wave LDS RAW is ordered by lgkmcnt); Vt/Ks covered above.
    // O += P V
    bf16x8 pf0 = *(const bf16x8*)&Ps[wq + lm][quad * 8];
    bf16x8 pf1 = *(const bf16x8*)&Ps[wq + lm][32 + quad * 8];
#pragma unroll
    for (int j = 0; j < 4; ++j) {
      bf16x8 v0f = *(const bf16x8*)&Vt[j * 16 + lm][quad * 8];
      bf16x8 v1f = *(const bf16x8*)&Vt[j * 16 + lm][32 + quad * 8];
      o[j] = MFMA16(pf0, v0f, o[j]);
      o[j] = MFMA16(pf1, v1f, o[j]);
    }
    __syncthreads();  // all reads done before next iter restages Ks/Vt
  }
#pragma unroll
  for (int r = 0; r < 4; ++r) {
    const float inv = 1.f / l_i[r];
    const size_t row = (size_t)(b * SL + qt * 64 + wq + quad * 4 + r) * CD + h * HD + lm;
#pragma unroll
    for (int j = 0; j < 4; ++j) ctx[row + j * 16] = f2bf(o[j][r] * inv);
  }
}

extern "C" void kernel_launch(void* const* d_in, const int* in_sizes, int n_in,
                              void* d_out, int out_size, void* d_ws, size_t ws_size,
                              hipStream_t stream) {
  const float* x     = (const float*)d_in[0];  // (8,32,32,768) fp32
  const float* w_qkv = (const float*)d_in[1];  // (2304,768) fp32
  const float* qg    = (const float*)d_in[2];  // (64,) fp32
  const float* kg    = (const float*)d_in[3];  // (64,) fp32
  const float* w_out = (const float*)d_in[4];  // (768,768) fp32
  // d_out: fp32.

  // ws: xb[8192*768] | wqb[2304*768] | wob[768*768] | qkv[8192*2304] | ctx[8192*768]  (bf16)
  unsigned short* xb  = (unsigned short*)d_ws;
  unsigned short* wqb = xb + (size_t)NB * SL * CD;
  unsigned short* wob = wqb + (size_t)QKVD * CD;
  unsigned short* qkv = wob + (size_t)CD * CD;
  unsigned short* ctx = qkv + (size_t)NB * SL * QKVD;

  const int M = NB * SL;  // 8192
  dim3 blk(256);
  // 0) fp32 -> bf16 converts
  conv_kernel<<<dim3(M * CD / 4 / 256), blk, 0, stream>>>(
      (const float4*)x, (ushort4*)xb, M * CD / 4);
  conv_kernel<<<dim3(QKVD * CD / 4 / 256), blk, 0, stream>>>(
      (const float4*)w_qkv, (ushort4*)wqb, QKVD * CD / 4);
  conv_kernel<<<dim3(CD * CD / 4 / 256), blk, 0, stream>>>(
      (const float4*)w_out, (ushort4*)wob, CD * CD / 4);
  // 1) qkv = x @ w_qkv^T  (bf16 out)
  gemm_mfma<0><<<dim3(QKVD / 128, M / 128), blk, 0, stream>>>(
      xb, wqb, qkv, M, QKVD, CD);
  // 2) rmsnorm + rope on q,k in place
  rmsrope_kernel<<<dim3(NB * SL * 2 * NHH / 4), blk, 0, stream>>>(qkv, qg, kg);
  // 3) attention -> ctx (bf16)
  attn_mfma<<<dim3(SL / 64, NHH, NB), blk, 0, stream>>>(qkv, ctx);
  // 4) out = ctx @ w_out^T  (fp32 out)
  gemm_mfma<1><<<dim3(CD / 128, M / 128), blk, 0, stream>>>(
      ctx, wob, d_out, M, CD, CD);
}

// Round 3
// 287.983 us; speedup vs baseline: 1.1915x; 1.0185x over previous
//
#include <hip/hip_runtime.h>
#include <math.h>

// Problem: B=8, L=1024, C=768, nH=12, hd=64, qkv dim 2304. fp32 in, fp32 out.
#define NB 8
#define SL 1024
#define CD 768
#define NHH 12
#define HD 64
#define QKVD 2304

typedef __attribute__((ext_vector_type(8))) __bf16 bf16x8;
typedef __attribute__((ext_vector_type(8))) unsigned short u16x8;
typedef __attribute__((ext_vector_type(4))) float f32x4;
#define MFMA16(a, b, c) __builtin_amdgcn_mfma_f32_16x16x32_bf16(a, b, c, 0, 0, 0)

__host__ __device__ __forceinline__ float bf2f(unsigned short u) {
  union { unsigned int i; float f; } v; v.i = ((unsigned int)u) << 16; return v.f;
}
__host__ __device__ __forceinline__ unsigned short f2bf(float f) {
  union { float ff; unsigned int i; } v; v.ff = f;
  unsigned int x = v.i;
  x += 0x7FFFu + ((x >> 16) & 1u);  // RNE
  return (unsigned short)(x >> 16);
}

// async global->LDS, 16B per lane. LDS dest must be linear in lane order.
__device__ __forceinline__ void gload_lds16(const void* g, void* l) {
  __builtin_amdgcn_global_load_lds(
      (const __attribute__((address_space(1))) unsigned int*)g,
      (__attribute__((address_space(3))) unsigned int*)l, 16, 0, 0);
}

// fp32 -> bf16 bulk convert (memory-bound).
__global__ __launch_bounds__(256) void conv_kernel(
    const float4* __restrict__ in, ushort4* __restrict__ out, int n4)
{
  int i = blockIdx.x * 256 + threadIdx.x;
  if (i < n4) {
    float4 v = in[i];
    ushort4 o;
    o.x = f2bf(v.x); o.y = f2bf(v.y); o.z = f2bf(v.z); o.w = f2bf(v.w);
    out[i] = o;
  }
}

// C[M,N] = A[M,K] @ B[N,K]^T, A,B bf16. CF32: store fp32 else bf16.
// 128x128 tile, BK=32, 256 threads = 4 waves in 2x2 grid, each wave 64x64
// via 4x4 grid of 16x16x32 MFMA. m97 structure: global_load_lds width-16
// staging into LINEAR LDS (no pad; global_load_lds needs contiguous dest).
template <int CF32>
__global__ __launch_bounds__(256) void gemm_mfma(
    const unsigned short* __restrict__ A, const unsigned short* __restrict__ B,
    void* __restrict__ Cv, int M, int N, int K)
{
  __shared__ alignas(16) unsigned short AsL[128 * 32];
  __shared__ alignas(16) unsigned short BsL[128 * 32];
  const int m0 = blockIdx.y * 128, n0 = blockIdx.x * 128;
  const int t = threadIdx.x;
  const int wave = t >> 6, lane = t & 63;
  const int wm = (wave >> 1) * 64, wn = (wave & 1) * 64;
  const int lm = lane & 15, quad = lane >> 4;
  const int sr = t >> 2, sc = (t & 3) * 8;  // staging: row (64 rows/call), col
  f32x4 acc[4][4];
#pragma unroll
  for (int i = 0; i < 4; ++i)
#pragma unroll
    for (int j = 0; j < 4; ++j)
#pragma unroll
      for (int r = 0; r < 4; ++r) acc[i][j][r] = 0.f;

  const unsigned short* ag = A + (size_t)(m0 + sr) * K + sc;
  const unsigned short* bg = B + (size_t)(n0 + sr) * K + sc;
  for (int k0 = 0; k0 < K; k0 += 32) {
    // 4KB per call (256 lanes x 16B); lane t -> LDS offset t*16 (linear).
    gload_lds16(ag + k0, &AsL[t * 8]);
    gload_lds16(ag + (size_t)64 * K + k0, &AsL[2048 + t * 8]);
    gload_lds16(bg + k0, &BsL[t * 8]);
    gload_lds16(bg + (size_t)64 * K + k0, &BsL[2048 + t * 8]);
    __syncthreads();  // drains vmcnt -> LDS staged
    bf16x8 af[4], bfr[4];
#pragma unroll
    for (int i = 0; i < 4; ++i)
      af[i] = *(const bf16x8*)&AsL[(wm + i * 16 + lm) * 32 + quad * 8];
#pragma unroll
    for (int j = 0; j < 4; ++j)
      bfr[j] = *(const bf16x8*)&BsL[(wn + j * 16 + lm) * 32 + quad * 8];
#pragma unroll
    for (int i = 0; i < 4; ++i)
#pragma unroll
      for (int j = 0; j < 4; ++j)
        acc[i][j] = MFMA16(af[i], bfr[j], acc[i][j]);
    __syncthreads();
  }
#pragma unroll
  for (int i = 0; i < 4; ++i) {
    const int row = m0 + wm + i * 16 + quad * 4;
#pragma unroll
    for (int r = 0; r < 4; ++r) {
      const size_t base = (size_t)(row + r) * N + n0 + wn + lm;
#pragma unroll
      for (int j = 0; j < 4; ++j) {
        if (CF32) ((float*)Cv)[base + j * 16] = acc[i][j][r];
        else ((unsigned short*)Cv)[base + j * 16] = f2bf(acc[i][j][r]);
      }
    }
  }
}

// RMSNorm(hd=64) + RoPE in place on q(s=0), k(s=1) planes of bf16 qkv ws.
// One 64-lane wave per (b,l,s,h) vector. Gammas fp32.
__global__ __launch_bounds__(256) void rmsrope_kernel(
    unsigned short* __restrict__ qkv,
    const float* __restrict__ qg, const float* __restrict__ kg)
{
  const int wid  = (int)((blockIdx.x * blockDim.x + threadIdx.x) >> 6);
  const int lane = threadIdx.x & 63;
  const int h = wid % NHH;
  const int s = (wid / NHH) & 1;
  const int l = (wid / (2 * NHH)) % SL;
  const int b = wid / (2 * NHH * SL);
  unsigned short* p = qkv + (((size_t)(b * SL + l) * 3 + s) * NHH + h) * HD + lane;
  float v = bf2f(*p);
  float ss = v * v;
#pragma unroll
  for (int off = 32; off; off >>= 1) ss += __shfl_xor(ss, off);
  float g = s ? kg[lane] : qg[lane];
  v = v * rsqrtf(ss * (1.0f / 64.0f) + 1e-6f) * g;
  float partner = __shfl_xor(v, 32);
  const int j = lane & 31;
  float ang = (float)l * exp2f((float)j * (-13.287712379549449f / 32.0f));
  float sn, cs;
  sincosf(ang, &sn, &cs);
  *p = f2bf((lane < 32) ? (v * cs - partner * sn) : (partner * sn + v * cs));
}

// MFMA flash attention. Block = (qtile 64, head, batch), 256 thr = 4 waves.
// Wave w owns q-rows [w*16, w*16+16) x all 64 keys/dims.
// v3 (re-run; round-2 bench was an infra failure, not a kernel failure):
//  - Double-buffered K and V tiles, ONE barrier per iteration. Next tile's
//    staging issues at the TOP of the iter (T3 minimum-2-phase + T14 split):
//    global-load latency hides under QK + softmax + PV of the current tile.
//  - K staged via global_load_lds (async, no VGPR roundtrip) into linear
//    [64][64] LDS with PRE-SWIZZLED global source (16B chunk ^= row&7, m173);
//    fragment reads apply the same XOR -> conflict-free without padding.
//  - Vt/Ps padded 72 -> 76 (stride 152B): bank word = (6*lm+4*quad)%32, all
//    16 lm distinct -> kills the measured Ps-write/Vt-read conflicts.
__global__ __launch_bounds__(256) void attn_mfma(
    const unsigned short* __restrict__ qkv, unsigned short* __restrict__ ctx)
{
  __shared__ alignas(16) unsigned short KsL[2][64 * 64];  // linear, src-swizzled
  __shared__ alignas(16) unsigned short Vt[2][64][76];    // [d][key]
  __shared__ alignas(16) unsigned short Ps[64][76];       // [qrow][key]
  // XCD swizzle: grid (16,12,8) x-major linear; XCD = bid & 7 (round-robin).
  const int bid = (int)(blockIdx.x + 16 * (blockIdx.y + 12 * blockIdx.z));
  const int nb = (bid & 7) * 192 + (bid >> 3);  // bijective: 1536 = 8*192
  const int qt = nb & 15;
  const int h = (nb >> 4) % 12;
  const int b = nb / 192;
  const int t = threadIdx.x, wave = t >> 6, lane = t & 63;
  const int lm = lane & 15, quad = lane >> 4;
  const int wq = wave * 16;
  const int vkey = t & 63, vds = (t >> 6) * 16;   // V staging assignment
  const int kr = t >> 3, kc = t & 7;              // K staging: row, 16B chunk

  // Per-(b,h) base pointers; key stride = 3*NHH*HD = 2304 ushorts.
  const unsigned short* base_k = qkv + (size_t)b * SL * QKVD + 1 * (NHH * HD) + h * HD;
  const unsigned short* base_v = qkv + (size_t)b * SL * QKVD + 2 * (NHH * HD) + h * HD;

  bf16x8 qf[2];
  {
    const unsigned short* qp =
        qkv + (((size_t)(b * SL + qt * 64 + wq + lm) * 3 + 0) * NHH + h) * HD;
    qf[0] = *(const bf16x8*)(qp + quad * 8);
    qf[1] = *(const bf16x8*)(qp + 32 + quad * 8);
  }
  f32x4 o[4];
  float m_i[4], l_i[4];
#pragma unroll
  for (int j = 0; j < 4; ++j) {
    m_i[j] = -INFINITY; l_i[j] = 0.f;
#pragma unroll
    for (int r = 0; r < 4; ++r) o[j][r] = 0.f;
  }

  // K tile stage: 2 gload calls (each: 256 thr x 16B = 4KB = 32 rows).
  // LDS[row][c] = Kglobal[row][c ^ (row&7)]  (16B chunks c=0..7).
  const int ksw = (kc ^ (kr & 7)) * 8;  // swizzled chunk, ushort offset
#define STAGE_K(KT, BUF)                                                      \
  {                                                                           \
    const unsigned short* k0p = base_k + (size_t)((KT)*64 + kr) * QKVD + ksw; \
    gload_lds16(k0p, &KsL[BUF][t * 8]);                                       \
    const unsigned short* k1p =                                               \
        base_k + (size_t)((KT)*64 + 32 + kr) * QKVD + ksw;                    \
    gload_lds16(k1p, &KsL[BUF][2048 + t * 8]);                                \
  }

  // prologue: stage tile 0 into buf 0
  STAGE_K(0, 0);
  {
    const unsigned short* vp = base_v + (size_t)vkey * QKVD + vds;
    u16x8 v0 = *(const u16x8*)(vp);
    u16x8 v1 = *(const u16x8*)(vp + 8);
#pragma unroll
    for (int e = 0; e < 8; ++e) {
      Vt[0][vds + e][vkey] = v0[e];
      Vt[0][vds + 8 + e][vkey] = v1[e];
    }
  }
  __syncthreads();

  for (int kt = 0; kt < 16; ++kt) {
    const int cur = kt & 1, nxt = cur ^ 1;
    const int ktn = (kt + 1) & 15;  // last iter re-stages tile 0 (unused)
    // ---- issue next tile's staging first (latency hides under compute) ----
    STAGE_K(ktn, nxt);
    const unsigned short* vp = base_v + (size_t)(ktn * 64 + vkey) * QKVD + vds;
    u16x8 v0n = *(const u16x8*)(vp);
    u16x8 v1n = *(const u16x8*)(vp + 8);
    // ---- S = Q K^T (K fragments from swizzled linear LDS) ----
    const unsigned short* Kb = KsL[cur];
    f32x4 s[4];
#pragma unroll
    for (int j = 0; j < 4; ++j) {
#pragma unroll
      for (int r = 0; r < 4; ++r) s[j][r] = 0.f;
      const int key = j * 16 + lm;
      bf16x8 k0f = *(const bf16x8*)&Kb[key * 64 + ((quad ^ (key & 7)) * 8)];
      bf16x8 k1f = *(const bf16x8*)&Kb[key * 64 + (((quad + 4) ^ (key & 7)) * 8)];
      s[j] = MFMA16(qf[0], k0f, s[j]);
      s[j] = MFMA16(qf[1], k1f, s[j]);
    }
    // ---- online softmax per row r (rows quad*4+r) ----
#pragma unroll
    for (int r = 0; r < 4; ++r) {
      float tm = -INFINITY;
#pragma unroll
      for (int j = 0; j < 4; ++j) { s[j][r] *= 0.125f; tm = fmaxf(tm, s[j][r]); }
#pragma unroll
      for (int off = 8; off; off >>= 1) tm = fmaxf(tm, __shfl_xor(tm, off));
      float mn = fmaxf(m_i[r], tm);
      float al = __expf(m_i[r] - mn);
      m_i[r] = mn;
      float rs = 0.f;
#pragma unroll
      for (int j = 0; j < 4; ++j) {
        float p = __expf(s[j][r] - mn);
        rs += p;
        Ps[wq + quad * 4 + r][j * 16 + lm] = f2bf(p);
      }
#pragma unroll
      for (int off = 8; off; off >>= 1) rs += __shfl_xor(rs, off);
      l_i[r] = l_i[r] * al + rs;
#pragma unroll
      for (int j = 0; j < 4; ++j) o[j][r] *= al;
    }
    // Ps rows [wq,wq+16) written+read by THIS wave only (in-wave lgkm order).
    // ---- O += P V ----
    bf16x8 pf0 = *(const bf16x8*)&Ps[wq + lm][quad * 8];
    bf16x8 pf1 = *(const bf16x8*)&Ps[wq + lm][32 + quad * 8];
#pragma unroll
    for (int j = 0; j < 4; ++j) {
      bf16x8 v0f = *(const bf16x8*)&Vt[cur][j * 16 + lm][quad * 8];
      bf16x8 v1f = *(const bf16x8*)&Vt[cur][j * 16 + lm][32 + quad * 8];
      o[j] = MFMA16(pf0, v0f, o[j]);
      o[j] = MFMA16(pf1, v1f, o[j]);
    }
    // ---- land next V tile (transpose-write into the other buffer) ----
#pragma unroll
    for (int e = 0; e < 8; ++e) {
      Vt[nxt][vds + e][vkey] = v0n[e];
      Vt[nxt][vds + 8 + e][vkey] = v1n[e];
    }
    __syncthreads();  // staged K (vmcnt) + Vt writes visible; cur reads done
  }
#pragma unroll
  for (int r = 0; r < 4; ++r) {
    const float inv = 1.f / l_i[r];
    const size_t row = (size_t)(b * SL + qt * 64 + wq + quad * 4 + r) * CD + h * HD + lm;
#pragma unroll
    for (int j = 0; j < 4; ++j) ctx[row + j * 16] = f2bf(o[j][r] * inv);
  }
#undef STAGE_K
}

extern "C" void kernel_launch(void* const* d_in, const int* in_sizes, int n_in,
                              void* d_out, int out_size, void* d_ws, size_t ws_size,
                              hipStream_t stream) {
  const float* x     = (const float*)d_in[0];  // (8,32,32,768) fp32
  const float* w_qkv = (const float*)d_in[1];  // (2304,768) fp32
  const float* qg    = (const float*)d_in[2];  // (64,) fp32
  const float* kg    = (const float*)d_in[3];  // (64,) fp32
  const float* w_out = (const float*)d_in[4];  // (768,768) fp32
  // d_out: fp32.

  // ws: xb[8192*768] | wqb[2304*768] | wob[768*768] | qkv[8192*2304] | ctx[8192*768]  (bf16)
  unsigned short* xb  = (unsigned short*)d_ws;
  unsigned short* wqb = xb + (size_t)NB * SL * CD;
  unsigned short* wob = wqb + (size_t)QKVD * CD;
  unsigned short* qkv = wob + (size_t)CD * CD;
  unsigned short* ctx = qkv + (size_t)NB * SL * QKVD;

  const int M = NB * SL;  // 8192
  dim3 blk(256);
  // 0) fp32 -> bf16 converts
  conv_kernel<<<dim3(M * CD / 4 / 256), blk, 0, stream>>>(
      (const float4*)x, (ushort4*)xb, M * CD / 4);
  conv_kernel<<<dim3(QKVD * CD / 4 / 256), blk, 0, stream>>>(
      (const float4*)w_qkv, (ushort4*)wqb, QKVD * CD / 4);
  conv_kernel<<<dim3(CD * CD / 4 / 256), blk, 0, stream>>>(
      (const float4*)w_out, (ushort4*)wob, CD * CD / 4);
  // 1) qkv = x @ w_qkv^T  (bf16 out)
  gemm_mfma<0><<<dim3(QKVD / 128, M / 128), blk, 0, stream>>>(
      xb, wqb, qkv, M, QKVD, CD);
  // 2) rmsnorm + rope on q,k in place
  rmsrope_kernel<<<dim3(NB * SL * 2 * NHH / 4), blk, 0, stream>>>(qkv, qg, kg);
  // 3) attention -> ctx (bf16)
  attn_mfma<<<dim3(SL / 64, NHH, NB), blk, 0, stream>>>(qkv, ctx);
  // 4) out = ctx @ w_out^T  (fp32 out)
  gemm_mfma<1><<<dim3(CD / 128, M / 128), blk, 0, stream>>>(
      ctx, wob, d_out, M, CD, CD);
}

// Round 4
// 245.749 us; speedup vs baseline: 1.3963x; 1.1719x over previous
//
#include <hip/hip_runtime.h>
#include <math.h>

// Problem: B=8, L=1024, C=768, nH=12, hd=64, qkv dim 2304. fp32 in, fp32 out.
#define NB 8
#define SL 1024
#define CD 768
#define NHH 12
#define HD 64
#define QKVD 2304

typedef __attribute__((ext_vector_type(8))) __bf16 bf16x8;
typedef __attribute__((ext_vector_type(8))) unsigned short u16x8;
typedef __attribute__((ext_vector_type(4))) float f32x4;
typedef __attribute__((ext_vector_type(16))) float f32x16;
typedef __attribute__((ext_vector_type(4))) unsigned int u32x4;
#define MFMA16(a, b, c) __builtin_amdgcn_mfma_f32_16x16x32_bf16(a, b, c, 0, 0, 0)
#define MFMA32(a, b, c) __builtin_amdgcn_mfma_f32_32x32x16_bf16(a, b, c, 0, 0, 0)

__host__ __device__ __forceinline__ float bf2f(unsigned short u) {
  union { unsigned int i; float f; } v; v.i = ((unsigned int)u) << 16; return v.f;
}
__host__ __device__ __forceinline__ unsigned short f2bf(float f) {
  union { float ff; unsigned int i; } v; v.ff = f;
  unsigned int x = v.i;
  x += 0x7FFFu + ((x >> 16) & 1u);  // RNE
  return (unsigned short)(x >> 16);
}
// pack two floats to bf16 pair (hw cvt, RNE) -> u32 (lo = first)
__device__ __forceinline__ unsigned int pkbf(float a, float b) {
  unsigned short ua = __builtin_bit_cast(unsigned short, (__bf16)a);
  unsigned short ub = __builtin_bit_cast(unsigned short, (__bf16)b);
  return ((unsigned int)ub << 16) | ua;
}

// async global->LDS, 16B per lane. LDS dest must be linear in lane order.
__device__ __forceinline__ void gload_lds16(const void* g, void* l) {
  __builtin_amdgcn_global_load_lds(
      (const __attribute__((address_space(1))) unsigned int*)g,
      (__attribute__((address_space(3))) unsigned int*)l, 16, 0, 0);
}

// fp32 -> bf16 bulk convert (memory-bound).
__global__ __launch_bounds__(256) void conv_kernel(
    const float4* __restrict__ in, ushort4* __restrict__ out, int n4)
{
  int i = blockIdx.x * 256 + threadIdx.x;
  if (i < n4) {
    float4 v = in[i];
    ushort4 o;
    o.x = f2bf(v.x); o.y = f2bf(v.y); o.z = f2bf(v.z); o.w = f2bf(v.w);
    out[i] = o;
  }
}

// C[M,N] = A[M,K] @ B[N,K]^T, A,B bf16. CF32: store fp32 else bf16.
// 128x128 tile, BK=32, 256 threads = 4 waves in 2x2 grid, each wave 64x64
// via 4x4 grid of 16x16x32 MFMA. m97 structure: global_load_lds width-16
// staging into LINEAR LDS (no pad; global_load_lds needs contiguous dest).
template <int CF32>
__global__ __launch_bounds__(256) void gemm_mfma(
    const unsigned short* __restrict__ A, const unsigned short* __restrict__ B,
    void* __restrict__ Cv, int M, int N, int K)
{
  __shared__ alignas(16) unsigned short AsL[128 * 32];
  __shared__ alignas(16) unsigned short BsL[128 * 32];
  const int m0 = blockIdx.y * 128, n0 = blockIdx.x * 128;
  const int t = threadIdx.x;
  const int wave = t >> 6, lane = t & 63;
  const int wm = (wave >> 1) * 64, wn = (wave & 1) * 64;
  const int lm = lane & 15, quad = lane >> 4;
  f32x4 acc[4][4];
#pragma unroll
  for (int i = 0; i < 4; ++i)
#pragma unroll
    for (int j = 0; j < 4; ++j)
#pragma unroll
      for (int r = 0; r < 4; ++r) acc[i][j][r] = 0.f;

  const int sr = t >> 2, sc = (t & 3) * 8;
  const unsigned short* ag = A + (size_t)(m0 + sr) * K + sc;
  const unsigned short* bg = B + (size_t)(n0 + sr) * K + sc;
  for (int k0 = 0; k0 < K; k0 += 32) {
    gload_lds16(ag + k0, &AsL[t * 8]);
    gload_lds16(ag + (size_t)64 * K + k0, &AsL[2048 + t * 8]);
    gload_lds16(bg + k0, &BsL[t * 8]);
    gload_lds16(bg + (size_t)64 * K + k0, &BsL[2048 + t * 8]);
    __syncthreads();  // drains vmcnt -> LDS staged
    bf16x8 af[4], bfr[4];
#pragma unroll
    for (int i = 0; i < 4; ++i)
      af[i] = *(const bf16x8*)&AsL[(wm + i * 16 + lm) * 32 + quad * 8];
#pragma unroll
    for (int j = 0; j < 4; ++j)
      bfr[j] = *(const bf16x8*)&BsL[(wn + j * 16 + lm) * 32 + quad * 8];
#pragma unroll
    for (int i = 0; i < 4; ++i)
#pragma unroll
      for (int j = 0; j < 4; ++j)
        acc[i][j] = MFMA16(af[i], bfr[j], acc[i][j]);
    __syncthreads();
  }
#pragma unroll
  for (int i = 0; i < 4; ++i) {
    const int row = m0 + wm + i * 16 + quad * 4;
#pragma unroll
    for (int r = 0; r < 4; ++r) {
      const size_t base = (size_t)(row + r) * N + n0 + wn + lm;
#pragma unroll
      for (int j = 0; j < 4; ++j) {
        if (CF32) ((float*)Cv)[base + j * 16] = acc[i][j][r];
        else ((unsigned short*)Cv)[base + j * 16] = f2bf(acc[i][j][r]);
      }
    }
  }
}

// RMSNorm(hd=64) + RoPE in place on q(s=0), k(s=1) planes of bf16 qkv ws.
// One 64-lane wave per (b,l,s,h) vector. Gammas fp32.
__global__ __launch_bounds__(256) void rmsrope_kernel(
    unsigned short* __restrict__ qkv,
    const float* __restrict__ qg, const float* __restrict__ kg)
{
  const int wid  = (int)((blockIdx.x * blockDim.x + threadIdx.x) >> 6);
  const int lane = threadIdx.x & 63;
  const int h = wid % NHH;
  const int s = (wid / NHH) & 1;
  const int l = (wid / (2 * NHH)) % SL;
  const int b = wid / (2 * NHH * SL);
  unsigned short* p = qkv + (((size_t)(b * SL + l) * 3 + s) * NHH + h) * HD + lane;
  float v = bf2f(*p);
  float ss = v * v;
#pragma unroll
  for (int off = 32; off; off >>= 1) ss += __shfl_xor(ss, off);
  float g = s ? kg[lane] : qg[lane];
  v = v * rsqrtf(ss * (1.0f / 64.0f) + 1e-6f) * g;
  float partner = __shfl_xor(v, 32);
  const int j = lane & 31;
  float ang = (float)l * exp2f((float)j * (-13.287712379549449f / 32.0f));
  float sn, cs;
  sincosf(ang, &sn, &cs);
  *p = f2bf((lane < 32) ? (v * cs - partner * sn) : (partner * sn + v * cs));
}

// MFMA flash attention, v4: swapped-operand 32x32 structure (m214/§B recipe).
// Block = (qtile 128, head, batch), 256 thr = 4 waves; wave owns 32 q-rows.
//  - S^T = mfma32(K, Q): lane holds S[key=crow(r,hi)][q=lane&31] for 32 keys
//    -> softmax fully in-register (31 fmax/add + one shfl_xor(32) merge).
//    crow(r,hi) = (r&3) + 8*(r>>2) + 4*hi (HW-verified C/D layout, m74/m101).
//  - P -> PV A-operand via in-register bf16 pack + 2 shfl_xor(32) per k-slot
//    (pairwise hi-half exchange; replaces the entire Ps LDS round-trip).
//  - O^T = mfma32(V^T, P): output q returns to lane&31 -> al-rescale and
//    1/l stay lane-local; C/D rows are d (contiguous 4-groups for stores).
//  - K via global_load_lds w16, src-swizzled (chunk ^= row&7); K/V double-
//    buffered, one barrier/iter (v3 structure, measured 0 bank conflicts).
__global__ __launch_bounds__(256) void attn_mfma(
    const unsigned short* __restrict__ qkv, unsigned short* __restrict__ ctx)
{
  __shared__ alignas(16) unsigned short KsL[2][64 * 64];  // linear, src-swizzled
  __shared__ alignas(16) unsigned short Vt[2][64][76];    // [d][key], stride 152B
  // XCD swizzle: grid (8,12,8) x-major linear; 768 = 8 XCD * 96.
  const int bid = (int)(blockIdx.x + 8 * (blockIdx.y + 12 * blockIdx.z));
  const int nb = (bid & 7) * 96 + (bid >> 3);  // bijective
  const int qt = nb & 7;
  const int h = (nb >> 3) % 12;
  const int b = nb / 96;
  const int t = threadIdx.x, wave = t >> 6, lane = t & 63;
  const int q_l = lane & 31, hi = lane >> 5;
  const int wq = wave * 32;                      // wave's q offset in 128-tile
  const int vkey = t & 63, vds = (t >> 6) * 16;  // V staging assignment
  const int kr = t >> 3, kc = t & 7;             // K staging: row, 16B chunk
  const float SCALE = 0.125f * 1.44269504088896340736f;  // 1/sqrt(64) * log2(e)

  const unsigned short* base_k = qkv + (size_t)b * SL * QKVD + (NHH * HD) + h * HD;
  const unsigned short* base_v = qkv + (size_t)b * SL * QKVD + 2 * (NHH * HD) + h * HD;

  // Q fragments (B-operand): Q[q = qt*128+wq+q_l][d = ds*16 + hi*8 + e]
  bf16x8 qf[4];
  {
    const unsigned short* qp =
        qkv + (((size_t)(b * SL + qt * 128 + wq + q_l) * 3 + 0) * NHH + h) * HD + hi * 8;
#pragma unroll
    for (int ds = 0; ds < 4; ++ds) qf[ds] = *(const bf16x8*)(qp + ds * 16);
  }
  f32x16 o0, o1;  // O^T[d = dt*32 + crow(r,hi)][q = q_l]
#pragma unroll
  for (int r = 0; r < 16; ++r) { o0[r] = 0.f; o1[r] = 0.f; }
  float m_i = -INFINITY, l_i = 0.f;  // log2-scaled units

  const int ksw = (kc ^ (kr & 7)) * 8;  // swizzled chunk, ushort offset
#define STAGE_K(KT, BUF)                                                      \
  {                                                                           \
    const unsigned short* k0p = base_k + (size_t)((KT)*64 + kr) * QKVD + ksw; \
    gload_lds16(k0p, &KsL[BUF][t * 8]);                                       \
    const unsigned short* k1p =                                               \
        base_k + (size_t)((KT)*64 + 32 + kr) * QKVD + ksw;                    \
    gload_lds16(k1p, &KsL[BUF][2048 + t * 8]);                                \
  }

  // prologue: stage tile 0 into buf 0
  STAGE_K(0, 0);
  {
    const unsigned short* vp = base_v + (size_t)vkey * QKVD + vds;
    u16x8 v0 = *(const u16x8*)(vp);
    u16x8 v1 = *(const u16x8*)(vp + 8);
#pragma unroll
    for (int e = 0; e < 8; ++e) {
      Vt[0][vds + e][vkey] = v0[e];
      Vt[0][vds + 8 + e][vkey] = v1[e];
    }
  }
  __syncthreads();

  for (int kt = 0; kt < 16; ++kt) {
    const int cur = kt & 1, nxt = cur ^ 1;
    const int ktn = (kt + 1) & 15;  // last iter re-stages tile 0 (unused)
    // ---- issue next tile's staging first (latency hides under compute) ----
    STAGE_K(ktn, nxt);
    const unsigned short* vp = base_v + (size_t)(ktn * 64 + vkey) * QKVD + vds;
    u16x8 v0n = *(const u16x8*)(vp);
    u16x8 v1n = *(const u16x8*)(vp + 8);
    // ---- S^T = K Q^T : st0 = keys 0-31, st1 = keys 32-63 ----
    const unsigned short* Kb = KsL[cur];
    f32x16 st0, st1;
#pragma unroll
    for (int r = 0; r < 16; ++r) { st0[r] = 0.f; st1[r] = 0.f; }
#pragma unroll
    for (int ds = 0; ds < 4; ++ds) {
      const int c = 2 * ds + hi;  // 16B chunk covering d = ds*16 + hi*8
      bf16x8 k0 = *(const bf16x8*)&Kb[q_l * 64 + ((c ^ (q_l & 7)) * 8)];
      bf16x8 k1 = *(const bf16x8*)&Kb[(32 + q_l) * 64 + ((c ^ (q_l & 7)) * 8)];
      st0 = MFMA32(k0, qf[ds], st0);
      st1 = MFMA32(k1, qf[ds], st1);
    }
    // ---- in-register online softmax (lane owns q = q_l; keys split by hi) --
    float tm = -INFINITY;
#pragma unroll
    for (int r = 0; r < 16; ++r) {
      st0[r] *= SCALE; st1[r] *= SCALE;
      tm = fmaxf(tm, fmaxf(st0[r], st1[r]));
    }
    tm = fmaxf(tm, __shfl_xor(tm, 32));
    const float mn = fmaxf(m_i, tm);
    const float al = __builtin_amdgcn_exp2f(m_i - mn);
    m_i = mn;
    float rs = 0.f;
#pragma unroll
    for (int r = 0; r < 16; ++r) {
      st0[r] = __builtin_amdgcn_exp2f(st0[r] - mn);
      st1[r] = __builtin_amdgcn_exp2f(st1[r] - mn);
      rs += st0[r] + st1[r];
    }
    rs += __shfl_xor(rs, 32);
    l_i = l_i * al + rs;
#pragma unroll
    for (int r = 0; r < 16; ++r) { o0[r] *= al; o1[r] *= al; }
    // ---- P exchange + PV: per k-slot, build A-frag and MFMA immediately ----
    // pa[ks] = P[q=q_l][key = ks*16 + hi*8 + e]; own half + partner half via
    // shfl_xor(32). send = hi ? low-quad : high-quad of the 8 packed values.
#define PV_KS(KS, PVEC, RL)                                              \
    {                                                                    \
      unsigned int a0 = pkbf(PVEC[RL + 0], PVEC[RL + 1]);                \
      unsigned int a1 = pkbf(PVEC[RL + 2], PVEC[RL + 3]);                \
      unsigned int b0 = pkbf(PVEC[RL + 4], PVEC[RL + 5]);                \
      unsigned int b1 = pkbf(PVEC[RL + 6], PVEC[RL + 7]);                \
      unsigned int s0 = hi ? a0 : b0, s1 = hi ? a1 : b1;                 \
      unsigned int r0 = __shfl_xor(s0, 32), r1 = __shfl_xor(s1, 32);     \
      u32x4 pw;                                                          \
      pw[0] = hi ? r0 : a0; pw[1] = hi ? r1 : a1;                        \
      pw[2] = hi ? b0 : r0; pw[3] = hi ? b1 : r1;                        \
      bf16x8 paf = __builtin_bit_cast(bf16x8, pw);                       \
      bf16x8 v0f = *(const bf16x8*)&Vt[cur][q_l][(KS)*16 + hi * 8];      \
      bf16x8 v1f = *(const bf16x8*)&Vt[cur][32 + q_l][(KS)*16 + hi * 8]; \
      o0 = MFMA32(v0f, paf, o0);                                         \
      o1 = MFMA32(v1f, paf, o1);                                         \
    }
    PV_KS(0, st0, 0)
    PV_KS(1, st0, 8)
    PV_KS(2, st1, 0)
    PV_KS(3, st1, 8)
#undef PV_KS
    // ---- land next V tile (transpose-write into the other buffer) ----
#pragma unroll
    for (int e = 0; e < 8; ++e) {
      Vt[nxt][vds + e][vkey] = v0n[e];
      Vt[nxt][vds + 8 + e][vkey] = v1n[e];
    }
    __syncthreads();  // staged K (vmcnt) + Vt writes visible; cur reads done
  }
  // ---- epilogue: O[q][d], q = q_l lane-local; d = dt*32 + 8g + 4hi + j ----
  const float inv = 1.f / l_i;
  const size_t row = (size_t)(b * SL + qt * 128 + wq + q_l) * CD + h * HD;
#pragma unroll
  for (int g = 0; g < 4; ++g) {
    uint2 w0, w1;
    w0.x = pkbf(o0[4 * g + 0] * inv, o0[4 * g + 1] * inv);
    w0.y = pkbf(o0[4 * g + 2] * inv, o0[4 * g + 3] * inv);
    *(uint2*)&ctx[row + 8 * g + 4 * hi] = w0;
    w1.x = pkbf(o1[4 * g + 0] * inv, o1[4 * g + 1] * inv);
    w1.y = pkbf(o1[4 * g + 2] * inv, o1[4 * g + 3] * inv);
    *(uint2*)&ctx[row + 32 + 8 * g + 4 * hi] = w1;
  }
#undef STAGE_K
}

extern "C" void kernel_launch(void* const* d_in, const int* in_sizes, int n_in,
                              void* d_out, int out_size, void* d_ws, size_t ws_size,
                              hipStream_t stream) {
  const float* x     = (const float*)d_in[0];  // (8,32,32,768) fp32
  const float* w_qkv = (const float*)d_in[1];  // (2304,768) fp32
  const float* qg    = (const float*)d_in[2];  // (64,) fp32
  const float* kg    = (const float*)d_in[3];  // (64,) fp32
  const float* w_out = (const float*)d_in[4];  // (768,768) fp32
  // d_out: fp32.

  // ws: xb[8192*768] | wqb[2304*768] | wob[768*768] | qkv[8192*2304] | ctx[8192*768]  (bf16)
  unsigned short* xb  = (unsigned short*)d_ws;
  unsigned short* wqb = xb + (size_t)NB * SL * CD;
  unsigned short* wob = wqb + (size_t)QKVD * CD;
  unsigned short* qkv = wob + (size_t)CD * CD;
  unsigned short* ctx = qkv + (size_t)NB * SL * QKVD;

  const int M = NB * SL;  // 8192
  dim3 blk(256);
  // 0) fp32 -> bf16 converts
  conv_kernel<<<dim3(M * CD / 4 / 256), blk, 0, stream>>>(
      (const float4*)x, (ushort4*)xb, M * CD / 4);
  conv_kernel<<<dim3(QKVD * CD / 4 / 256), blk, 0, stream>>>(
      (const float4*)w_qkv, (ushort4*)wqb, QKVD * CD / 4);
  conv_kernel<<<dim3(CD * CD / 4 / 256), blk, 0, stream>>>(
      (const float4*)w_out, (ushort4*)wob, CD * CD / 4);
  // 1) qkv = x @ w_qkv^T  (bf16 out)
  gemm_mfma<0><<<dim3(QKVD / 128, M / 128), blk, 0, stream>>>(
      xb, wqb, qkv, M, QKVD, CD);
  // 2) rmsnorm + rope on q,k in place
  rmsrope_kernel<<<dim3(NB * SL * 2 * NHH / 4), blk, 0, stream>>>(qkv, qg, kg);
  // 3) attention -> ctx (bf16)
  attn_mfma<<<dim3(SL / 128, NHH, NB), blk, 0, stream>>>(qkv, ctx);
  // 4) out = ctx @ w_out^T  (fp32 out)
  gemm_mfma<1><<<dim3(CD / 128, M / 128), blk, 0, stream>>>(
      ctx, wob, d_out, M, CD, CD);
}

// Round 5
// 244.825 us; speedup vs baseline: 1.4016x; 1.0038x over previous
//
#include <hip/hip_runtime.h>
#include <math.h>

// Problem: B=8, L=1024, C=768, nH=12, hd=64, qkv dim 2304. fp32 in, fp32 out.
#define NB 8
#define SL 1024
#define CD 768
#define NHH 12
#define HD 64
#define QKVD 2304

typedef __attribute__((ext_vector_type(8))) __bf16 bf16x8;
typedef __attribute__((ext_vector_type(8))) unsigned short u16x8;
typedef __attribute__((ext_vector_type(4))) float f32x4;
typedef __attribute__((ext_vector_type(16))) float f32x16;
typedef __attribute__((ext_vector_type(4))) unsigned int u32x4;
#define MFMA16(a, b, c) __builtin_amdgcn_mfma_f32_16x16x32_bf16(a, b, c, 0, 0, 0)
#define MFMA32(a, b, c) __builtin_amdgcn_mfma_f32_32x32x16_bf16(a, b, c, 0, 0, 0)

__host__ __device__ __forceinline__ float bf2f(unsigned short u) {
  union { unsigned int i; float f; } v; v.i = ((unsigned int)u) << 16; return v.f;
}
__host__ __device__ __forceinline__ unsigned short f2bf(float f) {
  union { float ff; unsigned int i; } v; v.ff = f;
  unsigned int x = v.i;
  x += 0x7FFFu + ((x >> 16) & 1u);  // RNE
  return (unsigned short)(x >> 16);
}
// pack two floats to bf16 pair (hw cvt, RNE) -> u32 (lo = first)
__device__ __forceinline__ unsigned int pkbf(float a, float b) {
  unsigned short ua = __builtin_bit_cast(unsigned short, (__bf16)a);
  unsigned short ub = __builtin_bit_cast(unsigned short, (__bf16)b);
  return ((unsigned int)ub << 16) | ua;
}

// async global->LDS, 16B per lane. LDS dest must be linear in lane order.
__device__ __forceinline__ void gload_lds16(const void* g, void* l) {
  __builtin_amdgcn_global_load_lds(
      (const __attribute__((address_space(1))) unsigned int*)g,
      (__attribute__((address_space(3))) unsigned int*)l, 16, 0, 0);
}

// fp32 -> bf16 bulk convert (memory-bound).
__global__ __launch_bounds__(256) void conv_kernel(
    const float4* __restrict__ in, ushort4* __restrict__ out, int n4)
{
  int i = blockIdx.x * 256 + threadIdx.x;
  if (i < n4) {
    float4 v = in[i];
    ushort4 o;
    o.x = f2bf(v.x); o.y = f2bf(v.y); o.z = f2bf(v.z); o.w = f2bf(v.w);
    out[i] = o;
  }
}

// C[M,N] = A[M,K] @ B[N,K]^T, A,B bf16.
// MODE 0: bf16 out. MODE 1: fp32 out. MODE 2: bf16 out with fused
// RMSNorm(hd=64)+RoPE on q/k head-columns (the qkv projection epilogue).
// 128x128 tile, BK=32, 256 threads = 4 waves in 2x2 grid, each wave 64x64
// via 4x4 grid of 16x16x32 MFMA; global_load_lds w16 staging, linear LDS.
template <int MODE>
__global__ __launch_bounds__(256) void gemm_mfma(
    const unsigned short* __restrict__ A, const unsigned short* __restrict__ B,
    void* __restrict__ Cv, int M, int N, int K,
    const float* __restrict__ qg, const float* __restrict__ kg)
{
  __shared__ alignas(16) unsigned short AsL[128 * 32];
  __shared__ alignas(16) unsigned short BsL[128 * 32];
  const int m0 = blockIdx.y * 128, n0 = blockIdx.x * 128;
  const int t = threadIdx.x;
  const int wave = t >> 6, lane = t & 63;
  const int wm = (wave >> 1) * 64, wn = (wave & 1) * 64;
  const int lm = lane & 15, quad = lane >> 4;
  f32x4 acc[4][4];
#pragma unroll
  for (int i = 0; i < 4; ++i)
#pragma unroll
    for (int j = 0; j < 4; ++j)
#pragma unroll
      for (int r = 0; r < 4; ++r) acc[i][j][r] = 0.f;

  const int sr = t >> 2, sc = (t & 3) * 8;
  const unsigned short* ag = A + (size_t)(m0 + sr) * K + sc;
  const unsigned short* bg = B + (size_t)(n0 + sr) * K + sc;
  for (int k0 = 0; k0 < K; k0 += 32) {
    gload_lds16(ag + k0, &AsL[t * 8]);
    gload_lds16(ag + (size_t)64 * K + k0, &AsL[2048 + t * 8]);
    gload_lds16(bg + k0, &BsL[t * 8]);
    gload_lds16(bg + (size_t)64 * K + k0, &BsL[2048 + t * 8]);
    __syncthreads();  // drains vmcnt -> LDS staged
    bf16x8 af[4], bfr[4];
#pragma unroll
    for (int i = 0; i < 4; ++i)
      af[i] = *(const bf16x8*)&AsL[(wm + i * 16 + lm) * 32 + quad * 8];
#pragma unroll
    for (int j = 0; j < 4; ++j)
      bfr[j] = *(const bf16x8*)&BsL[(wn + j * 16 + lm) * 32 + quad * 8];
#pragma unroll
    for (int i = 0; i < 4; ++i)
#pragma unroll
      for (int j = 0; j < 4; ++j)
        acc[i][j] = MFMA16(af[i], bfr[j], acc[i][j]);
    __syncthreads();
  }

  // ---- fused RMSNorm + RoPE epilogue (MODE 2, q/k planes only) ----
  // Wave covers cols [n0+wn, n0+wn+64) = exactly one head (hd=64; 128-aligned
  // tiles never straddle the s-plane boundaries at col 768/1536).
  if (MODE == 2 && (n0 + wn) < 2 * CD) {
    const float* gam = ((n0 + wn) >= CD) ? kg : qg;
    float g4[4];
#pragma unroll
    for (int j = 0; j < 4; ++j) g4[j] = gam[j * 16 + lm];
    const float C1 = -13.287712379549449f / 32.0f;  // -log2(10000)/32
    const float if0 = exp2f((float)lm * C1);          // invfreq(dd=lm)
    const float if1 = exp2f((float)(16 + lm) * C1);   // invfreq(dd=16+lm)
    unsigned short* Cs = (unsigned short*)Cv;
#pragma unroll
    for (int i = 0; i < 4; ++i) {
      const int row = m0 + wm + i * 16 + quad * 4;
#pragma unroll
      for (int r = 0; r < 4; ++r) {
        float v0 = acc[i][0][r], v1 = acc[i][1][r];
        float v2 = acc[i][2][r], v3 = acc[i][3][r];
        float ssq = v0 * v0 + v1 * v1 + v2 * v2 + v3 * v3;
#pragma unroll
        for (int off = 8; off; off >>= 1) ssq += __shfl_xor(ssq, off);
        const float sc2 = rsqrtf(ssq * (1.0f / 64.0f) + 1e-6f);
        v0 *= sc2 * g4[0]; v1 *= sc2 * g4[1];
        v2 *= sc2 * g4[2]; v3 *= sc2 * g4[3];
        const int l = (row + r) & (SL - 1);
        float sn0, cs0, sn1, cs1;
        sincosf((float)l * if0, &sn0, &cs0);
        sincosf((float)l * if1, &sn1, &cs1);
        const size_t base = (size_t)(row + r) * N + n0 + wn + lm;
        Cs[base +  0] = f2bf(v0 * cs0 - v2 * sn0);   // dd = lm
        Cs[base + 16] = f2bf(v1 * cs1 - v3 * sn1);   // dd = 16+lm
        Cs[base + 32] = f2bf(v0 * sn0 + v2 * cs0);   // dd = 32+lm
        Cs[base + 48] = f2bf(v1 * sn1 + v3 * cs1);   // dd = 48+lm
      }
    }
    return;
  }

#pragma unroll
  for (int i = 0; i < 4; ++i) {
    const int row = m0 + wm + i * 16 + quad * 4;
#pragma unroll
    for (int r = 0; r < 4; ++r) {
      const size_t base = (size_t)(row + r) * N + n0 + wn + lm;
#pragma unroll
      for (int j = 0; j < 4; ++j) {
        if (MODE == 1) ((float*)Cv)[base + j * 16] = acc[i][j][r];
        else ((unsigned short*)Cv)[base + j * 16] = f2bf(acc[i][j][r]);
      }
    }
  }
}

// MFMA flash attention, v5 (on v4's swapped-operand 32x32 structure):
//  - defer-max (T13, THR=8 log2-units): skip O/l rescale when the running
//    max grew < THR (wave-uniform branch) — kills 32 muls + 1 exp most iters.
//  - SCALE folded into the exp2 argument (fma) — kills the 32-mul scale pass.
//  - 4-chain max tree (shorter dep chain, max3-fusable).
//  - s_setprio(1) around MFMA clusters (T5, +4-7% attn measured).
__global__ __launch_bounds__(256) void attn_mfma(
    const unsigned short* __restrict__ qkv, unsigned short* __restrict__ ctx)
{
  __shared__ alignas(16) unsigned short KsL[2][64 * 64];  // linear, src-swizzled
  __shared__ alignas(16) unsigned short Vt[2][64][76];    // [d][key], stride 152B
  // XCD swizzle: grid (8,12,8) x-major linear; 768 = 8 XCD * 96.
  const int bid = (int)(blockIdx.x + 8 * (blockIdx.y + 12 * blockIdx.z));
  const int nb = (bid & 7) * 96 + (bid >> 3);  // bijective
  const int qt = nb & 7;
  const int h = (nb >> 3) % 12;
  const int b = nb / 96;
  const int t = threadIdx.x, wave = t >> 6, lane = t & 63;
  const int q_l = lane & 31, hi = lane >> 5;
  const int wq = wave * 32;                      // wave's q offset in 128-tile
  const int vkey = t & 63, vds = (t >> 6) * 16;  // V staging assignment
  const int kr = t >> 3, kc = t & 7;             // K staging: row, 16B chunk
  const float SCALE = 0.125f * 1.44269504088896340736f;  // 1/sqrt(64) * log2(e)

  const unsigned short* base_k = qkv + (size_t)b * SL * QKVD + (NHH * HD) + h * HD;
  const unsigned short* base_v = qkv + (size_t)b * SL * QKVD + 2 * (NHH * HD) + h * HD;

  // Q fragments (B-operand): Q[q = qt*128+wq+q_l][d = ds*16 + hi*8 + e]
  bf16x8 qf[4];
  {
    const unsigned short* qp =
        qkv + (((size_t)(b * SL + qt * 128 + wq + q_l) * 3 + 0) * NHH + h) * HD + hi * 8;
#pragma unroll
    for (int ds = 0; ds < 4; ++ds) qf[ds] = *(const bf16x8*)(qp + ds * 16);
  }
  f32x16 o0, o1;  // O^T[d = dt*32 + crow(r,hi)][q = q_l]
#pragma unroll
  for (int r = 0; r < 16; ++r) { o0[r] = 0.f; o1[r] = 0.f; }
  float m_i = -INFINITY, l_i = 0.f;  // log2-scaled units

  const int ksw = (kc ^ (kr & 7)) * 8;  // swizzled chunk, ushort offset
#define STAGE_K(KT, BUF)                                                      \
  {                                                                           \
    const unsigned short* k0p = base_k + (size_t)((KT)*64 + kr) * QKVD + ksw; \
    gload_lds16(k0p, &KsL[BUF][t * 8]);                                       \
    const unsigned short* k1p =                                               \
        base_k + (size_t)((KT)*64 + 32 + kr) * QKVD + ksw;                    \
    gload_lds16(k1p, &KsL[BUF][2048 + t * 8]);                                \
  }

  // prologue: stage tile 0 into buf 0
  STAGE_K(0, 0);
  {
    const unsigned short* vp = base_v + (size_t)vkey * QKVD + vds;
    u16x8 v0 = *(const u16x8*)(vp);
    u16x8 v1 = *(const u16x8*)(vp + 8);
#pragma unroll
    for (int e = 0; e < 8; ++e) {
      Vt[0][vds + e][vkey] = v0[e];
      Vt[0][vds + 8 + e][vkey] = v1[e];
    }
  }
  __syncthreads();

  for (int kt = 0; kt < 16; ++kt) {
    const int cur = kt & 1, nxt = cur ^ 1;
    const int ktn = (kt + 1) & 15;  // last iter re-stages tile 0 (unused)
    // ---- issue next tile's staging first (latency hides under compute) ----
    STAGE_K(ktn, nxt);
    const unsigned short* vp = base_v + (size_t)(ktn * 64 + vkey) * QKVD + vds;
    u16x8 v0n = *(const u16x8*)(vp);
    u16x8 v1n = *(const u16x8*)(vp + 8);
    // ---- S^T = K Q^T : st0 = keys 0-31, st1 = keys 32-63 ----
    const unsigned short* Kb = KsL[cur];
    f32x16 st0, st1;
#pragma unroll
    for (int r = 0; r < 16; ++r) { st0[r] = 0.f; st1[r] = 0.f; }
    __builtin_amdgcn_s_setprio(1);
#pragma unroll
    for (int ds = 0; ds < 4; ++ds) {
      const int c = 2 * ds + hi;  // 16B chunk covering d = ds*16 + hi*8
      bf16x8 k0 = *(const bf16x8*)&Kb[q_l * 64 + ((c ^ (q_l & 7)) * 8)];
      bf16x8 k1 = *(const bf16x8*)&Kb[(32 + q_l) * 64 + ((c ^ (q_l & 7)) * 8)];
      st0 = MFMA32(k0, qf[ds], st0);
      st1 = MFMA32(k1, qf[ds], st1);
    }
    __builtin_amdgcn_s_setprio(0);
    // ---- online softmax, log2 domain, defer-max ----
    float t0 = fmaxf(st0[0], st1[0]), t1 = fmaxf(st0[1], st1[1]);
    float t2 = fmaxf(st0[2], st1[2]), t3 = fmaxf(st0[3], st1[3]);
#pragma unroll
    for (int r = 4; r < 16; r += 4) {
      t0 = fmaxf(t0, fmaxf(st0[r + 0], st1[r + 0]));
      t1 = fmaxf(t1, fmaxf(st0[r + 1], st1[r + 1]));
      t2 = fmaxf(t2, fmaxf(st0[r + 2], st1[r + 2]));
      t3 = fmaxf(t3, fmaxf(st0[r + 3], st1[r + 3]));
    }
    float tm = fmaxf(fmaxf(t0, t1), fmaxf(t2, t3)) * SCALE;
    tm = fmaxf(tm, __shfl_xor(tm, 32));  // full 64-key max for this q
    if (!__all(tm - m_i <= 8.0f)) {      // rescale only on real max growth
      const float mn = fmaxf(m_i, tm);
      const float al = __builtin_amdgcn_exp2f(m_i - mn);
      m_i = mn;
      l_i *= al;
#pragma unroll
      for (int r = 0; r < 16; ++r) { o0[r] *= al; o1[r] *= al; }
    }
    float rs = 0.f;
#pragma unroll
    for (int r = 0; r < 16; ++r) {
      st0[r] = __builtin_amdgcn_exp2f(fmaf(st0[r], SCALE, -m_i));
      st1[r] = __builtin_amdgcn_exp2f(fmaf(st1[r], SCALE, -m_i));
      rs += st0[r] + st1[r];
    }
    rs += __shfl_xor(rs, 32);
    l_i += rs;
    // ---- P exchange + PV: per k-slot, build A-frag and MFMA immediately ----
#define PV_KS(KS, PVEC, RL)                                              \
    {                                                                    \
      unsigned int a0 = pkbf(PVEC[RL + 0], PVEC[RL + 1]);                \
      unsigned int a1 = pkbf(PVEC[RL + 2], PVEC[RL + 3]);                \
      unsigned int b0 = pkbf(PVEC[RL + 4], PVEC[RL + 5]);                \
      unsigned int b1 = pkbf(PVEC[RL + 6], PVEC[RL + 7]);                \
      unsigned int s0 = hi ? a0 : b0, s1 = hi ? a1 : b1;                 \
      unsigned int r0 = __shfl_xor(s0, 32), r1 = __shfl_xor(s1, 32);     \
      u32x4 pw;                                                          \
      pw[0] = hi ? r0 : a0; pw[1] = hi ? r1 : a1;                        \
      pw[2] = hi ? b0 : r0; pw[3] = hi ? b1 : r1;                        \
      bf16x8 paf = __builtin_bit_cast(bf16x8, pw);                       \
      bf16x8 v0f = *(const bf16x8*)&Vt[cur][q_l][(KS)*16 + hi * 8];      \
      bf16x8 v1f = *(const bf16x8*)&Vt[cur][32 + q_l][(KS)*16 + hi * 8]; \
      __builtin_amdgcn_s_setprio(1);                                     \
      o0 = MFMA32(v0f, paf, o0);                                         \
      o1 = MFMA32(v1f, paf, o1);                                         \
      __builtin_amdgcn_s_setprio(0);                                     \
    }
    PV_KS(0, st0, 0)
    PV_KS(1, st0, 8)
    PV_KS(2, st1, 0)
    PV_KS(3, st1, 8)
#undef PV_KS
    // ---- land next V tile (transpose-write into the other buffer) ----
#pragma unroll
    for (int e = 0; e < 8; ++e) {
      Vt[nxt][vds + e][vkey] = v0n[e];
      Vt[nxt][vds + 8 + e][vkey] = v1n[e];
    }
    __syncthreads();  // staged K (vmcnt) + Vt writes visible; cur reads done
  }
  // ---- epilogue: O[q][d], q = q_l lane-local; d = dt*32 + 8g + 4hi + j ----
  const float inv = 1.f / l_i;
  const size_t row = (size_t)(b * SL + qt * 128 + wq + q_l) * CD + h * HD;
#pragma unroll
  for (int g = 0; g < 4; ++g) {
    uint2 w0, w1;
    w0.x = pkbf(o0[4 * g + 0] * inv, o0[4 * g + 1] * inv);
    w0.y = pkbf(o0[4 * g + 2] * inv, o0[4 * g + 3] * inv);
    *(uint2*)&ctx[row + 8 * g + 4 * hi] = w0;
    w1.x = pkbf(o1[4 * g + 0] * inv, o1[4 * g + 1] * inv);
    w1.y = pkbf(o1[4 * g + 2] * inv, o1[4 * g + 3] * inv);
    *(uint2*)&ctx[row + 32 + 8 * g + 4 * hi] = w1;
  }
#undef STAGE_K
}

extern "C" void kernel_launch(void* const* d_in, const int* in_sizes, int n_in,
                              void* d_out, int out_size, void* d_ws, size_t ws_size,
                              hipStream_t stream) {
  const float* x     = (const float*)d_in[0];  // (8,32,32,768) fp32
  const float* w_qkv = (const float*)d_in[1];  // (2304,768) fp32
  const float* qg    = (const float*)d_in[2];  // (64,) fp32
  const float* kg    = (const float*)d_in[3];  // (64,) fp32
  const float* w_out = (const float*)d_in[4];  // (768,768) fp32
  // d_out: fp32.

  // ws: xb[8192*768] | wqb[2304*768] | wob[768*768] | qkv[8192*2304] | ctx[8192*768]  (bf16)
  unsigned short* xb  = (unsigned short*)d_ws;
  unsigned short* wqb = xb + (size_t)NB * SL * CD;
  unsigned short* wob = wqb + (size_t)QKVD * CD;
  unsigned short* qkv = wob + (size_t)CD * CD;
  unsigned short* ctx = qkv + (size_t)NB * SL * QKVD;

  const int M = NB * SL;  // 8192
  dim3 blk(256);
  // 0) fp32 -> bf16 converts
  conv_kernel<<<dim3(M * CD / 4 / 256), blk, 0, stream>>>(
      (const float4*)x, (ushort4*)xb, M * CD / 4);
  conv_kernel<<<dim3(QKVD * CD / 4 / 256), blk, 0, stream>>>(
      (const float4*)w_qkv, (ushort4*)wqb, QKVD * CD / 4);
  conv_kernel<<<dim3(CD * CD / 4 / 256), blk, 0, stream>>>(
      (const float4*)w_out, (ushort4*)wob, CD * CD / 4);
  // 1) qkv = x @ w_qkv^T with fused RMSNorm+RoPE on q,k head-columns
  gemm_mfma<2><<<dim3(QKVD / 128, M / 128), blk, 0, stream>>>(
      xb, wqb, qkv, M, QKVD, CD, qg, kg);
  // 2) attention -> ctx (bf16)
  attn_mfma<<<dim3(SL / 128, NHH, NB), blk, 0, stream>>>(qkv, ctx);
  // 3) out = ctx @ w_out^T  (fp32 out)
  gemm_mfma<1><<<dim3(CD / 128, M / 128), blk, 0, stream>>>(
      ctx, wob, d_out, M, CD, CD, nullptr, nullptr);
}

// Round 6
// 218.966 us; speedup vs baseline: 1.5671x; 1.1181x over previous
//
#include <hip/hip_runtime.h>
#include <math.h>

// Problem: B=8, L=1024, C=768, nH=12, hd=64, qkv dim 2304. fp32 in, fp32 out.
#define NB 8
#define SL 1024
#define CD 768
#define NHH 12
#define HD 64
#define QKVD 2304

typedef __attribute__((ext_vector_type(8))) __bf16 bf16x8;
typedef __attribute__((ext_vector_type(8))) unsigned short u16x8;
typedef __attribute__((ext_vector_type(4))) float f32x4;
typedef __attribute__((ext_vector_type(16))) float f32x16;
typedef __attribute__((ext_vector_type(4))) unsigned int u32x4;
#define MFMA16(a, b, c) __builtin_amdgcn_mfma_f32_16x16x32_bf16(a, b, c, 0, 0, 0)
#define MFMA32(a, b, c) __builtin_amdgcn_mfma_f32_32x32x16_bf16(a, b, c, 0, 0, 0)

__host__ __device__ __forceinline__ float bf2f(unsigned short u) {
  union { unsigned int i; float f; } v; v.i = ((unsigned int)u) << 16; return v.f;
}
__host__ __device__ __forceinline__ unsigned short f2bf(float f) {
  union { float ff; unsigned int i; } v; v.ff = f;
  unsigned int x = v.i;
  x += 0x7FFFu + ((x >> 16) & 1u);  // RNE
  return (unsigned short)(x >> 16);
}
// pack two floats to bf16 pair (hw cvt, RNE) -> u32 (lo = first)
__device__ __forceinline__ unsigned int pkbf(float a, float b) {
  unsigned short ua = __builtin_bit_cast(unsigned short, (__bf16)a);
  unsigned short ub = __builtin_bit_cast(unsigned short, (__bf16)b);
  return ((unsigned int)ub << 16) | ua;
}

// async global->LDS, 16B per lane. LDS dest must be linear in lane order.
__device__ __forceinline__ void gload_lds16(const void* g, void* l) {
  __builtin_amdgcn_global_load_lds(
      (const __attribute__((address_space(1))) unsigned int*)g,
      (__attribute__((address_space(3))) unsigned int*)l, 16, 0, 0);
}

// fp32 -> bf16 bulk convert (memory-bound).
__global__ __launch_bounds__(256) void conv_kernel(
    const float4* __restrict__ in, ushort4* __restrict__ out, int n4)
{
  int i = blockIdx.x * 256 + threadIdx.x;
  if (i < n4) {
    float4 v = in[i];
    ushort4 o;
    o.x = f2bf(v.x); o.y = f2bf(v.y); o.z = f2bf(v.z); o.w = f2bf(v.w);
    out[i] = o;
  }
}

// RoPE cos/sin table: rt[l*32 + j] = {cos, sin}(l * invfreq(j)), l<1024, j<32.
__global__ __launch_bounds__(256) void rope_tab_kernel(float2* __restrict__ rt)
{
  int i = blockIdx.x * 256 + threadIdx.x;  // 32768 entries
  int l = i >> 5, j = i & 31;
  float ang = (float)l * exp2f((float)j * (-13.287712379549449f / 32.0f));
  float sn, cs;
  sincosf(ang, &sn, &cs);
  rt[i] = make_float2(cs, sn);
}

// C[M,N] = A[M,K] @ B[N,K]^T, A,B bf16.
// MODE 0: bf16 out. MODE 1: fp32 out. MODE 2: bf16 out with fused
// RMSNorm(hd=64)+RoPE (table-driven) on q/k head-columns.
// v6: 2-phase double-buffered gload_lds staging (stage next K-step BEFORE
// computing current; one barrier/iter, drain after compute) + 16B-chunk
// src-swizzle g(row)=(row>>1)&3 -> LDS reads are 2 lanes/bank (free).
// XCD-aware block swizzle (grid %8==0 for both gemm launches).
template <int MODE>
__global__ __launch_bounds__(256) void gemm_mfma(
    const unsigned short* __restrict__ A, const unsigned short* __restrict__ B,
    void* __restrict__ Cv, int M, int N, int K,
    const float* __restrict__ qg, const float* __restrict__ kg,
    const float2* __restrict__ rt)
{
  __shared__ alignas(16) unsigned short AsL[2][128 * 32];
  __shared__ alignas(16) unsigned short BsL[2][128 * 32];
  // XCD swizzle (bijective: nwg % 8 == 0 for both gemm grids)
  const int bid = (int)(blockIdx.x + gridDim.x * blockIdx.y);
  const int cpx = (int)(gridDim.x * gridDim.y) >> 3;
  const int nb = (bid & 7) * cpx + (bid >> 3);
  const int bx = nb % (int)gridDim.x, by = nb / (int)gridDim.x;
  const int m0 = by * 128, n0 = bx * 128;
  const int t = threadIdx.x;
  const int wave = t >> 6, lane = t & 63;
  const int wm = (wave >> 1) * 64, wn = (wave & 1) * 64;
  const int lm = lane & 15, quad = lane >> 4;
  const int rq = (quad ^ ((lm >> 1) & 3)) * 8;  // swizzled read chunk offset
  f32x4 acc[4][4];
#pragma unroll
  for (int i = 0; i < 4; ++i)
#pragma unroll
    for (int j = 0; j < 4; ++j)
#pragma unroll
      for (int r = 0; r < 4; ++r) acc[i][j][r] = 0.f;

  // staging: thread t covers row sr (of 64-row half), 16B chunk kc4;
  // source pre-swizzled: LDS[r][c] = G[r][c ^ ((r>>1)&3)].
  const int sr = t >> 2, kc4 = t & 3;
  const int scs = (kc4 ^ ((sr >> 1) & 3)) * 8;
  const unsigned short* ag = A + (size_t)(m0 + sr) * K + scs;
  const unsigned short* bg = B + (size_t)(n0 + sr) * K + scs;
#define STAGE_G(K0, BUF)                                          \
  {                                                               \
    gload_lds16(ag + (K0), &AsL[BUF][t * 8]);                     \
    gload_lds16(ag + (size_t)64 * K + (K0), &AsL[BUF][2048 + t * 8]); \
    gload_lds16(bg + (K0), &BsL[BUF][t * 8]);                     \
    gload_lds16(bg + (size_t)64 * K + (K0), &BsL[BUF][2048 + t * 8]); \
  }

  STAGE_G(0, 0);
  __syncthreads();
  int cur = 0;
  for (int k0 = 0; k0 < K; k0 += 32) {
    if (k0 + 32 < K) STAGE_G(k0 + 32, cur ^ 1);  // issue next (hides latency)
    bf16x8 af[4], bfr[4];
#pragma unroll
    for (int i = 0; i < 4; ++i)
      af[i] = *(const bf16x8*)&AsL[cur][(wm + i * 16 + lm) * 32 + rq];
#pragma unroll
    for (int j = 0; j < 4; ++j)
      bfr[j] = *(const bf16x8*)&BsL[cur][(wn + j * 16 + lm) * 32 + rq];
    __builtin_amdgcn_s_setprio(1);
#pragma unroll
    for (int i = 0; i < 4; ++i)
#pragma unroll
      for (int j = 0; j < 4; ++j)
        acc[i][j] = MFMA16(af[i], bfr[j], acc[i][j]);
    __builtin_amdgcn_s_setprio(0);
    __syncthreads();  // drains vmcnt (next-tile loads had MFMA time to land)
    cur ^= 1;
  }
#undef STAGE_G

  // ---- fused RMSNorm + RoPE epilogue (MODE 2, q/k planes only) ----
  // Wave covers cols [n0+wn, n0+wn+64) = exactly one head (hd=64; 128-aligned
  // tiles never straddle the s-plane boundaries at col 768/1536).
  if (MODE == 2 && (n0 + wn) < 2 * CD) {
    const float* gam = ((n0 + wn) >= CD) ? kg : qg;
    float g4[4];
#pragma unroll
    for (int j = 0; j < 4; ++j) g4[j] = gam[j * 16 + lm];
    unsigned short* Cs = (unsigned short*)Cv;
#pragma unroll
    for (int i = 0; i < 4; ++i) {
      const int row = m0 + wm + i * 16 + quad * 4;
#pragma unroll
      for (int r = 0; r < 4; ++r) {
        float v0 = acc[i][0][r], v1 = acc[i][1][r];
        float v2 = acc[i][2][r], v3 = acc[i][3][r];
        float ssq = v0 * v0 + v1 * v1 + v2 * v2 + v3 * v3;
#pragma unroll
        for (int off = 8; off; off >>= 1) ssq += __shfl_xor(ssq, off);
        const float sc2 = rsqrtf(ssq * (1.0f / 64.0f) + 1e-6f);
        v0 *= sc2 * g4[0]; v1 *= sc2 * g4[1];
        v2 *= sc2 * g4[2]; v3 *= sc2 * g4[3];
        const int l = (row + r) & (SL - 1);
        const float2 t0 = rt[l * 32 + lm];        // {cos,sin} dd=lm
        const float2 t1 = rt[l * 32 + 16 + lm];   // {cos,sin} dd=16+lm
        const size_t base = (size_t)(row + r) * N + n0 + wn + lm;
        Cs[base +  0] = f2bf(v0 * t0.x - v2 * t0.y);   // dd = lm
        Cs[base + 16] = f2bf(v1 * t1.x - v3 * t1.y);   // dd = 16+lm
        Cs[base + 32] = f2bf(v0 * t0.y + v2 * t0.x);   // dd = 32+lm
        Cs[base + 48] = f2bf(v1 * t1.y + v3 * t1.x);   // dd = 48+lm
      }
    }
    return;
  }

#pragma unroll
  for (int i = 0; i < 4; ++i) {
    const int row = m0 + wm + i * 16 + quad * 4;
#pragma unroll
    for (int r = 0; r < 4; ++r) {
      const size_t base = (size_t)(row + r) * N + n0 + wn + lm;
#pragma unroll
      for (int j = 0; j < 4; ++j) {
        if (MODE == 1) ((float*)Cv)[base + j * 16] = acc[i][j][r];
        else ((unsigned short*)Cv)[base + j * 16] = f2bf(acc[i][j][r]);
      }
    }
  }
}

// MFMA flash attention, v5 structure (unchanged this round):
// swapped-operand 32x32, in-register softmax (log2 domain), defer-max (T13),
// setprio around MFMA (T5), dbuf K/V, 1 barrier/iter, XCD swizzle.
__global__ __launch_bounds__(256) void attn_mfma(
    const unsigned short* __restrict__ qkv, unsigned short* __restrict__ ctx)
{
  __shared__ alignas(16) unsigned short KsL[2][64 * 64];  // linear, src-swizzled
  __shared__ alignas(16) unsigned short Vt[2][64][76];    // [d][key], stride 152B
  // XCD swizzle: grid (8,12,8) x-major linear; 768 = 8 XCD * 96.
  const int bid = (int)(blockIdx.x + 8 * (blockIdx.y + 12 * blockIdx.z));
  const int nb = (bid & 7) * 96 + (bid >> 3);  // bijective
  const int qt = nb & 7;
  const int h = (nb >> 3) % 12;
  const int b = nb / 96;
  const int t = threadIdx.x, wave = t >> 6, lane = t & 63;
  const int q_l = lane & 31, hi = lane >> 5;
  const int wq = wave * 32;                      // wave's q offset in 128-tile
  const int vkey = t & 63, vds = (t >> 6) * 16;  // V staging assignment
  const int kr = t >> 3, kc = t & 7;             // K staging: row, 16B chunk
  const float SCALE = 0.125f * 1.44269504088896340736f;  // 1/sqrt(64) * log2(e)

  const unsigned short* base_k = qkv + (size_t)b * SL * QKVD + (NHH * HD) + h * HD;
  const unsigned short* base_v = qkv + (size_t)b * SL * QKVD + 2 * (NHH * HD) + h * HD;

  // Q fragments (B-operand): Q[q = qt*128+wq+q_l][d = ds*16 + hi*8 + e]
  bf16x8 qf[4];
  {
    const unsigned short* qp =
        qkv + (((size_t)(b * SL + qt * 128 + wq + q_l) * 3 + 0) * NHH + h) * HD + hi * 8;
#pragma unroll
    for (int ds = 0; ds < 4; ++ds) qf[ds] = *(const bf16x8*)(qp + ds * 16);
  }
  f32x16 o0, o1;  // O^T[d = dt*32 + crow(r,hi)][q = q_l]
#pragma unroll
  for (int r = 0; r < 16; ++r) { o0[r] = 0.f; o1[r] = 0.f; }
  float m_i = -INFINITY, l_i = 0.f;  // log2-scaled units

  const int ksw = (kc ^ (kr & 7)) * 8;  // swizzled chunk, ushort offset
#define STAGE_K(KT, BUF)                                                      \
  {                                                                           \
    const unsigned short* k0p = base_k + (size_t)((KT)*64 + kr) * QKVD + ksw; \
    gload_lds16(k0p, &KsL[BUF][t * 8]);                                       \
    const unsigned short* k1p =                                               \
        base_k + (size_t)((KT)*64 + 32 + kr) * QKVD + ksw;                    \
    gload_lds16(k1p, &KsL[BUF][2048 + t * 8]);                                \
  }

  // prologue: stage tile 0 into buf 0
  STAGE_K(0, 0);
  {
    const unsigned short* vp = base_v + (size_t)vkey * QKVD + vds;
    u16x8 v0 = *(const u16x8*)(vp);
    u16x8 v1 = *(const u16x8*)(vp + 8);
#pragma unroll
    for (int e = 0; e < 8; ++e) {
      Vt[0][vds + e][vkey] = v0[e];
      Vt[0][vds + 8 + e][vkey] = v1[e];
    }
  }
  __syncthreads();

  for (int kt = 0; kt < 16; ++kt) {
    const int cur = kt & 1, nxt = cur ^ 1;
    const int ktn = (kt + 1) & 15;  // last iter re-stages tile 0 (unused)
    // ---- issue next tile's staging first (latency hides under compute) ----
    STAGE_K(ktn, nxt);
    const unsigned short* vp = base_v + (size_t)(ktn * 64 + vkey) * QKVD + vds;
    u16x8 v0n = *(const u16x8*)(vp);
    u16x8 v1n = *(const u16x8*)(vp + 8);
    // ---- S^T = K Q^T : st0 = keys 0-31, st1 = keys 32-63 ----
    const unsigned short* Kb = KsL[cur];
    f32x16 st0, st1;
#pragma unroll
    for (int r = 0; r < 16; ++r) { st0[r] = 0.f; st1[r] = 0.f; }
    __builtin_amdgcn_s_setprio(1);
#pragma unroll
    for (int ds = 0; ds < 4; ++ds) {
      const int c = 2 * ds + hi;  // 16B chunk covering d = ds*16 + hi*8
      bf16x8 k0 = *(const bf16x8*)&Kb[q_l * 64 + ((c ^ (q_l & 7)) * 8)];
      bf16x8 k1 = *(const bf16x8*)&Kb[(32 + q_l) * 64 + ((c ^ (q_l & 7)) * 8)];
      st0 = MFMA32(k0, qf[ds], st0);
      st1 = MFMA32(k1, qf[ds], st1);
    }
    __builtin_amdgcn_s_setprio(0);
    // ---- online softmax, log2 domain, defer-max ----
    float t0 = fmaxf(st0[0], st1[0]), t1 = fmaxf(st0[1], st1[1]);
    float t2 = fmaxf(st0[2], st1[2]), t3 = fmaxf(st0[3], st1[3]);
#pragma unroll
    for (int r = 4; r < 16; r += 4) {
      t0 = fmaxf(t0, fmaxf(st0[r + 0], st1[r + 0]));
      t1 = fmaxf(t1, fmaxf(st0[r + 1], st1[r + 1]));
      t2 = fmaxf(t2, fmaxf(st0[r + 2], st1[r + 2]));
      t3 = fmaxf(t3, fmaxf(st0[r + 3], st1[r + 3]));
    }
    float tm = fmaxf(fmaxf(t0, t1), fmaxf(t2, t3)) * SCALE;
    tm = fmaxf(tm, __shfl_xor(tm, 32));  // full 64-key max for this q
    if (!__all(tm - m_i <= 8.0f)) {      // rescale only on real max growth
      const float mn = fmaxf(m_i, tm);
      const float al = __builtin_amdgcn_exp2f(m_i - mn);
      m_i = mn;
      l_i *= al;
#pragma unroll
      for (int r = 0; r < 16; ++r) { o0[r] *= al; o1[r] *= al; }
    }
    float rs = 0.f;
#pragma unroll
    for (int r = 0; r < 16; ++r) {
      st0[r] = __builtin_amdgcn_exp2f(fmaf(st0[r], SCALE, -m_i));
      st1[r] = __builtin_amdgcn_exp2f(fmaf(st1[r], SCALE, -m_i));
      rs += st0[r] + st1[r];
    }
    rs += __shfl_xor(rs, 32);
    l_i += rs;
    // ---- P exchange + PV: per k-slot, build A-frag and MFMA immediately ----
#define PV_KS(KS, PVEC, RL)                                              \
    {                                                                    \
      unsigned int a0 = pkbf(PVEC[RL + 0], PVEC[RL + 1]);                \
      unsigned int a1 = pkbf(PVEC[RL + 2], PVEC[RL + 3]);                \
      unsigned int b0 = pkbf(PVEC[RL + 4], PVEC[RL + 5]);                \
      unsigned int b1 = pkbf(PVEC[RL + 6], PVEC[RL + 7]);                \
      unsigned int s0 = hi ? a0 : b0, s1 = hi ? a1 : b1;                 \
      unsigned int r0 = __shfl_xor(s0, 32), r1 = __shfl_xor(s1, 32);     \
      u32x4 pw;                                                          \
      pw[0] = hi ? r0 : a0; pw[1] = hi ? r1 : a1;                        \
      pw[2] = hi ? b0 : r0; pw[3] = hi ? b1 : r1;                        \
      bf16x8 paf = __builtin_bit_cast(bf16x8, pw);                       \
      bf16x8 v0f = *(const bf16x8*)&Vt[cur][q_l][(KS)*16 + hi * 8];      \
      bf16x8 v1f = *(const bf16x8*)&Vt[cur][32 + q_l][(KS)*16 + hi * 8]; \
      __builtin_amdgcn_s_setprio(1);                                     \
      o0 = MFMA32(v0f, paf, o0);                                         \
      o1 = MFMA32(v1f, paf, o1);                                         \
      __builtin_amdgcn_s_setprio(0);                                     \
    }
    PV_KS(0, st0, 0)
    PV_KS(1, st0, 8)
    PV_KS(2, st1, 0)
    PV_KS(3, st1, 8)
#undef PV_KS
    // ---- land next V tile (transpose-write into the other buffer) ----
#pragma unroll
    for (int e = 0; e < 8; ++e) {
      Vt[nxt][vds + e][vkey] = v0n[e];
      Vt[nxt][vds + 8 + e][vkey] = v1n[e];
    }
    __syncthreads();  // staged K (vmcnt) + Vt writes visible; cur reads done
  }
  // ---- epilogue: O[q][d], q = q_l lane-local; d = dt*32 + 8g + 4hi + j ----
  const float inv = 1.f / l_i;
  const size_t row = (size_t)(b * SL + qt * 128 + wq + q_l) * CD + h * HD;
#pragma unroll
  for (int g = 0; g < 4; ++g) {
    uint2 w0, w1;
    w0.x = pkbf(o0[4 * g + 0] * inv, o0[4 * g + 1] * inv);
    w0.y = pkbf(o0[4 * g + 2] * inv, o0[4 * g + 3] * inv);
    *(uint2*)&ctx[row + 8 * g + 4 * hi] = w0;
    w1.x = pkbf(o1[4 * g + 0] * inv, o1[4 * g + 1] * inv);
    w1.y = pkbf(o1[4 * g + 2] * inv, o1[4 * g + 3] * inv);
    *(uint2*)&ctx[row + 32 + 8 * g + 4 * hi] = w1;
  }
#undef STAGE_K
}

extern "C" void kernel_launch(void* const* d_in, const int* in_sizes, int n_in,
                              void* d_out, int out_size, void* d_ws, size_t ws_size,
                              hipStream_t stream) {
  const float* x     = (const float*)d_in[0];  // (8,32,32,768) fp32
  const float* w_qkv = (const float*)d_in[1];  // (2304,768) fp32
  const float* qg    = (const float*)d_in[2];  // (64,) fp32
  const float* kg    = (const float*)d_in[3];  // (64,) fp32
  const float* w_out = (const float*)d_in[4];  // (768,768) fp32
  // d_out: fp32.

  // ws: xb | wqb | wob | qkv | ctx (bf16) | rtab (float2, 256KB)
  unsigned short* xb  = (unsigned short*)d_ws;
  unsigned short* wqb = xb + (size_t)NB * SL * CD;
  unsigned short* wob = wqb + (size_t)QKVD * CD;
  unsigned short* qkv = wob + (size_t)CD * CD;
  unsigned short* ctx = qkv + (size_t)NB * SL * QKVD;
  float2* rtab = (float2*)(ctx + (size_t)NB * SL * CD);

  const int M = NB * SL;  // 8192
  dim3 blk(256);
  // 0) fp32 -> bf16 converts + RoPE table
  conv_kernel<<<dim3(M * CD / 4 / 256), blk, 0, stream>>>(
      (const float4*)x, (ushort4*)xb, M * CD / 4);
  conv_kernel<<<dim3(QKVD * CD / 4 / 256), blk, 0, stream>>>(
      (const float4*)w_qkv, (ushort4*)wqb, QKVD * CD / 4);
  conv_kernel<<<dim3(CD * CD / 4 / 256), blk, 0, stream>>>(
      (const float4*)w_out, (ushort4*)wob, CD * CD / 4);
  rope_tab_kernel<<<dim3(SL * 32 / 256), blk, 0, stream>>>(rtab);
  // 1) qkv = x @ w_qkv^T with fused RMSNorm+RoPE on q,k head-columns
  gemm_mfma<2><<<dim3(QKVD / 128, M / 128), blk, 0, stream>>>(
      xb, wqb, qkv, M, QKVD, CD, qg, kg, rtab);
  // 2) attention -> ctx (bf16)
  attn_mfma<<<dim3(SL / 128, NHH, NB), blk, 0, stream>>>(qkv, ctx);
  // 3) out = ctx @ w_out^T  (fp32 out)
  gemm_mfma<1><<<dim3(CD / 128, M / 128), blk, 0, stream>>>(
      ctx, wob, d_out, M, CD, CD, nullptr, nullptr, nullptr);
}

// Round 7
// 212.645 us; speedup vs baseline: 1.6137x; 1.0297x over previous
//
#include <hip/hip_runtime.h>
#include <math.h>

// Problem: B=8, L=1024, C=768, nH=12, hd=64, qkv dim 2304. fp32 in, fp32 out.
#define NB 8
#define SL 1024
#define CD 768
#define NHH 12
#define HD 64
#define QKVD 2304

typedef __attribute__((ext_vector_type(8))) __bf16 bf16x8;
typedef __attribute__((ext_vector_type(8))) unsigned short u16x8;
typedef __attribute__((ext_vector_type(4))) float f32x4;
typedef __attribute__((ext_vector_type(16))) float f32x16;
typedef __attribute__((ext_vector_type(4))) unsigned int u32x4;
#define MFMA16(a, b, c) __builtin_amdgcn_mfma_f32_16x16x32_bf16(a, b, c, 0, 0, 0)
#define MFMA32(a, b, c) __builtin_amdgcn_mfma_f32_32x32x16_bf16(a, b, c, 0, 0, 0)

__host__ __device__ __forceinline__ float bf2f(unsigned short u) {
  union { unsigned int i; float f; } v; v.i = ((unsigned int)u) << 16; return v.f;
}
__host__ __device__ __forceinline__ unsigned short f2bf(float f) {
  union { float ff; unsigned int i; } v; v.ff = f;
  unsigned int x = v.i;
  x += 0x7FFFu + ((x >> 16) & 1u);  // RNE
  return (unsigned short)(x >> 16);
}
// pack two floats to bf16 pair (hw cvt, RNE) -> u32 (lo = first)
__device__ __forceinline__ unsigned int pkbf(float a, float b) {
  unsigned short ua = __builtin_bit_cast(unsigned short, (__bf16)a);
  unsigned short ub = __builtin_bit_cast(unsigned short, (__bf16)b);
  return ((unsigned int)ub << 16) | ua;
}

// async global->LDS, 16B per lane. LDS dest must be linear in lane order.
__device__ __forceinline__ void gload_lds16(const void* g, void* l) {
  __builtin_amdgcn_global_load_lds(
      (const __attribute__((address_space(1))) unsigned int*)g,
      (__attribute__((address_space(3))) unsigned int*)l, 16, 0, 0);
}

// Fused prep: 3x fp32->bf16 convert + RoPE cos/sin table, ONE launch
// (launch gaps ~8us each dominate these tiny kernels).
#define PN0 (NB * SL * CD / 4)   // x float4s
#define PN1 (QKVD * CD / 4)      // w_qkv
#define PN2 (CD * CD / 4)        // w_out
#define PN3 (SL * 32)            // rope table entries
__global__ __launch_bounds__(256) void prep_kernel(
    const float4* __restrict__ x, const float4* __restrict__ wq,
    const float4* __restrict__ wo, ushort4* __restrict__ xb,
    ushort4* __restrict__ wqb, ushort4* __restrict__ wob,
    float2* __restrict__ rt)
{
  int i = blockIdx.x * 256 + threadIdx.x;
  if (i < PN0 + PN1 + PN2) {
    const float4* src; ushort4* dst; int k;
    if (i < PN0) { src = x; dst = xb; k = i; }
    else if (i < PN0 + PN1) { src = wq; dst = wqb; k = i - PN0; }
    else { src = wo; dst = wob; k = i - PN0 - PN1; }
    float4 v = src[k];
    ushort4 o;
    o.x = f2bf(v.x); o.y = f2bf(v.y); o.z = f2bf(v.z); o.w = f2bf(v.w);
    dst[k] = o;
  } else {
    int k = i - PN0 - PN1 - PN2;  // < PN3 by grid sizing
    int l = k >> 5, j = k & 31;
    float ang = (float)l * exp2f((float)j * (-13.287712379549449f / 32.0f));
    float sn, cs;
    sincosf(ang, &sn, &cs);
    rt[k] = make_float2(cs, sn);
  }
}

// C[M,N] = A[M,K] @ B[N,K]^T, A,B bf16.
// MODE 0: bf16 out. MODE 1: fp32 out. MODE 2: bf16 out with fused
// RMSNorm(hd=64)+RoPE (table-driven) on q/k head-columns.
// 2-phase double-buffered gload_lds staging + 16B-chunk src-swizzle
// g(row)=(row>>1)&3 (LDS reads 2 lanes/bank = free) + XCD block swizzle.
template <int MODE>
__global__ __launch_bounds__(256) void gemm_mfma(
    const unsigned short* __restrict__ A, const unsigned short* __restrict__ B,
    void* __restrict__ Cv, int M, int N, int K,
    const float* __restrict__ qg, const float* __restrict__ kg,
    const float2* __restrict__ rt)
{
  __shared__ alignas(16) unsigned short AsL[2][128 * 32];
  __shared__ alignas(16) unsigned short BsL[2][128 * 32];
  // XCD swizzle (bijective: nwg % 8 == 0 for both gemm grids)
  const int bid = (int)(blockIdx.x + gridDim.x * blockIdx.y);
  const int cpx = (int)(gridDim.x * gridDim.y) >> 3;
  const int nb = (bid & 7) * cpx + (bid >> 3);
  const int bx = nb % (int)gridDim.x, by = nb / (int)gridDim.x;
  const int m0 = by * 128, n0 = bx * 128;
  const int t = threadIdx.x;
  const int wave = t >> 6, lane = t & 63;
  const int wm = (wave >> 1) * 64, wn = (wave & 1) * 64;
  const int lm = lane & 15, quad = lane >> 4;
  const int rq = (quad ^ ((lm >> 1) & 3)) * 8;  // swizzled read chunk offset
  f32x4 acc[4][4];
#pragma unroll
  for (int i = 0; i < 4; ++i)
#pragma unroll
    for (int j = 0; j < 4; ++j)
#pragma unroll
      for (int r = 0; r < 4; ++r) acc[i][j][r] = 0.f;

  // staging: thread t covers row sr (of 64-row half), 16B chunk kc4;
  // source pre-swizzled: LDS[r][c] = G[r][c ^ ((r>>1)&3)].
  const int sr = t >> 2, kc4 = t & 3;
  const int scs = (kc4 ^ ((sr >> 1) & 3)) * 8;
  const unsigned short* ag = A + (size_t)(m0 + sr) * K + scs;
  const unsigned short* bg = B + (size_t)(n0 + sr) * K + scs;
#define STAGE_G(K0, BUF)                                          \
  {                                                               \
    gload_lds16(ag + (K0), &AsL[BUF][t * 8]);                     \
    gload_lds16(ag + (size_t)64 * K + (K0), &AsL[BUF][2048 + t * 8]); \
    gload_lds16(bg + (K0), &BsL[BUF][t * 8]);                     \
    gload_lds16(bg + (size_t)64 * K + (K0), &BsL[BUF][2048 + t * 8]); \
  }

  STAGE_G(0, 0);
  __syncthreads();
  int cur = 0;
  for (int k0 = 0; k0 < K; k0 += 32) {
    if (k0 + 32 < K) STAGE_G(k0 + 32, cur ^ 1);  // issue next (hides latency)
    bf16x8 af[4], bfr[4];
#pragma unroll
    for (int i = 0; i < 4; ++i)
      af[i] = *(const bf16x8*)&AsL[cur][(wm + i * 16 + lm) * 32 + rq];
#pragma unroll
    for (int j = 0; j < 4; ++j)
      bfr[j] = *(const bf16x8*)&BsL[cur][(wn + j * 16 + lm) * 32 + rq];
    __builtin_amdgcn_s_setprio(1);
#pragma unroll
    for (int i = 0; i < 4; ++i)
#pragma unroll
      for (int j = 0; j < 4; ++j)
        acc[i][j] = MFMA16(af[i], bfr[j], acc[i][j]);
    __builtin_amdgcn_s_setprio(0);
    __syncthreads();  // drains vmcnt (next-tile loads had MFMA time to land)
    cur ^= 1;
  }
#undef STAGE_G

  // ---- fused RMSNorm + RoPE epilogue (MODE 2, q/k planes only) ----
  if (MODE == 2 && (n0 + wn) < 2 * CD) {
    const float* gam = ((n0 + wn) >= CD) ? kg : qg;
    float g4[4];
#pragma unroll
    for (int j = 0; j < 4; ++j) g4[j] = gam[j * 16 + lm];
    unsigned short* Cs = (unsigned short*)Cv;
#pragma unroll
    for (int i = 0; i < 4; ++i) {
      const int row = m0 + wm + i * 16 + quad * 4;
#pragma unroll
      for (int r = 0; r < 4; ++r) {
        float v0 = acc[i][0][r], v1 = acc[i][1][r];
        float v2 = acc[i][2][r], v3 = acc[i][3][r];
        float ssq = v0 * v0 + v1 * v1 + v2 * v2 + v3 * v3;
#pragma unroll
        for (int off = 8; off; off >>= 1) ssq += __shfl_xor(ssq, off);
        const float sc2 = rsqrtf(ssq * (1.0f / 64.0f) + 1e-6f);
        v0 *= sc2 * g4[0]; v1 *= sc2 * g4[1];
        v2 *= sc2 * g4[2]; v3 *= sc2 * g4[3];
        const int l = (row + r) & (SL - 1);
        const float2 t0 = rt[l * 32 + lm];        // {cos,sin} dd=lm
        const float2 t1 = rt[l * 32 + 16 + lm];   // {cos,sin} dd=16+lm
        const size_t base = (size_t)(row + r) * N + n0 + wn + lm;
        Cs[base +  0] = f2bf(v0 * t0.x - v2 * t0.y);   // dd = lm
        Cs[base + 16] = f2bf(v1 * t1.x - v3 * t1.y);   // dd = 16+lm
        Cs[base + 32] = f2bf(v0 * t0.y + v2 * t0.x);   // dd = 32+lm
        Cs[base + 48] = f2bf(v1 * t1.y + v3 * t1.x);   // dd = 48+lm
      }
    }
    return;
  }

#pragma unroll
  for (int i = 0; i < 4; ++i) {
    const int row = m0 + wm + i * 16 + quad * 4;
#pragma unroll
    for (int r = 0; r < 4; ++r) {
      const size_t base = (size_t)(row + r) * N + n0 + wn + lm;
#pragma unroll
      for (int j = 0; j < 4; ++j) {
        if (MODE == 1) ((float*)Cv)[base + j * 16] = acc[i][j][r];
        else ((unsigned short*)Cv)[base + j * 16] = f2bf(acc[i][j][r]);
      }
    }
  }
}

// MFMA flash attention, v7: v5 structure with the PV setprio churn removed
// (r6 counters: occupancy 23.7->16%, dur 64.5->69.5 after r5's 8 toggles/iter;
// keep defer-max + folded scale which cut VALUBusy 56->41%). QK setprio kept.
__global__ __launch_bounds__(256) void attn_mfma(
    const unsigned short* __restrict__ qkv, unsigned short* __restrict__ ctx)
{
  __shared__ alignas(16) unsigned short KsL[2][64 * 64];  // linear, src-swizzled
  __shared__ alignas(16) unsigned short Vt[2][64][76];    // [d][key], stride 152B
  // XCD swizzle: grid (8,12,8) x-major linear; 768 = 8 XCD * 96.
  const int bid = (int)(blockIdx.x + 8 * (blockIdx.y + 12 * blockIdx.z));
  const int nb = (bid & 7) * 96 + (bid >> 3);  // bijective
  const int qt = nb & 7;
  const int h = (nb >> 3) % 12;
  const int b = nb / 96;
  const int t = threadIdx.x, wave = t >> 6, lane = t & 63;
  const int q_l = lane & 31, hi = lane >> 5;
  const int wq = wave * 32;                      // wave's q offset in 128-tile
  const int vkey = t & 63, vds = (t >> 6) * 16;  // V staging assignment
  const int kr = t >> 3, kc = t & 7;             // K staging: row, 16B chunk
  const float SCALE = 0.125f * 1.44269504088896340736f;  // 1/sqrt(64) * log2(e)

  const unsigned short* base_k = qkv + (size_t)b * SL * QKVD + (NHH * HD) + h * HD;
  const unsigned short* base_v = qkv + (size_t)b * SL * QKVD + 2 * (NHH * HD) + h * HD;

  // Q fragments (B-operand): Q[q = qt*128+wq+q_l][d = ds*16 + hi*8 + e]
  bf16x8 qf[4];
  {
    const unsigned short* qp =
        qkv + (((size_t)(b * SL + qt * 128 + wq + q_l) * 3 + 0) * NHH + h) * HD + hi * 8;
#pragma unroll
    for (int ds = 0; ds < 4; ++ds) qf[ds] = *(const bf16x8*)(qp + ds * 16);
  }
  f32x16 o0, o1;  // O^T[d = dt*32 + crow(r,hi)][q = q_l]
#pragma unroll
  for (int r = 0; r < 16; ++r) { o0[r] = 0.f; o1[r] = 0.f; }
  float m_i = -INFINITY, l_i = 0.f;  // log2-scaled units

  const int ksw = (kc ^ (kr & 7)) * 8;  // swizzled chunk, ushort offset
#define STAGE_K(KT, BUF)                                                      \
  {                                                                           \
    const unsigned short* k0p = base_k + (size_t)((KT)*64 + kr) * QKVD + ksw; \
    gload_lds16(k0p, &KsL[BUF][t * 8]);                                       \
    const unsigned short* k1p =                                               \
        base_k + (size_t)((KT)*64 + 32 + kr) * QKVD + ksw;                    \
    gload_lds16(k1p, &KsL[BUF][2048 + t * 8]);                                \
  }

  // prologue: stage tile 0 into buf 0
  STAGE_K(0, 0);
  {
    const unsigned short* vp = base_v + (size_t)vkey * QKVD + vds;
    u16x8 v0 = *(const u16x8*)(vp);
    u16x8 v1 = *(const u16x8*)(vp + 8);
#pragma unroll
    for (int e = 0; e < 8; ++e) {
      Vt[0][vds + e][vkey] = v0[e];
      Vt[0][vds + 8 + e][vkey] = v1[e];
    }
  }
  __syncthreads();

  for (int kt = 0; kt < 16; ++kt) {
    const int cur = kt & 1, nxt = cur ^ 1;
    const int ktn = (kt + 1) & 15;  // last iter re-stages tile 0 (unused)
    // ---- issue next tile's staging first (latency hides under compute) ----
    STAGE_K(ktn, nxt);
    const unsigned short* vp = base_v + (size_t)(ktn * 64 + vkey) * QKVD + vds;
    u16x8 v0n = *(const u16x8*)(vp);
    u16x8 v1n = *(const u16x8*)(vp + 8);
    // ---- S^T = K Q^T : st0 = keys 0-31, st1 = keys 32-63 ----
    const unsigned short* Kb = KsL[cur];
    f32x16 st0, st1;
#pragma unroll
    for (int r = 0; r < 16; ++r) { st0[r] = 0.f; st1[r] = 0.f; }
    __builtin_amdgcn_s_setprio(1);
#pragma unroll
    for (int ds = 0; ds < 4; ++ds) {
      const int c = 2 * ds + hi;  // 16B chunk covering d = ds*16 + hi*8
      bf16x8 k0 = *(const bf16x8*)&Kb[q_l * 64 + ((c ^ (q_l & 7)) * 8)];
      bf16x8 k1 = *(const bf16x8*)&Kb[(32 + q_l) * 64 + ((c ^ (q_l & 7)) * 8)];
      st0 = MFMA32(k0, qf[ds], st0);
      st1 = MFMA32(k1, qf[ds], st1);
    }
    __builtin_amdgcn_s_setprio(0);
    // ---- online softmax, log2 domain, defer-max ----
    float t0 = fmaxf(st0[0], st1[0]), t1 = fmaxf(st0[1], st1[1]);
    float t2 = fmaxf(st0[2], st1[2]), t3 = fmaxf(st0[3], st1[3]);
#pragma unroll
    for (int r = 4; r < 16; r += 4) {
      t0 = fmaxf(t0, fmaxf(st0[r + 0], st1[r + 0]));
      t1 = fmaxf(t1, fmaxf(st0[r + 1], st1[r + 1]));
      t2 = fmaxf(t2, fmaxf(st0[r + 2], st1[r + 2]));
      t3 = fmaxf(t3, fmaxf(st0[r + 3], st1[r + 3]));
    }
    float tm = fmaxf(fmaxf(t0, t1), fmaxf(t2, t3)) * SCALE;
    tm = fmaxf(tm, __shfl_xor(tm, 32));  // full 64-key max for this q
    if (!__all(tm - m_i <= 8.0f)) {      // rescale only on real max growth
      const float mn = fmaxf(m_i, tm);
      const float al = __builtin_amdgcn_exp2f(m_i - mn);
      m_i = mn;
      l_i *= al;
#pragma unroll
      for (int r = 0; r < 16; ++r) { o0[r] *= al; o1[r] *= al; }
    }
    float rs = 0.f;
#pragma unroll
    for (int r = 0; r < 16; ++r) {
      st0[r] = __builtin_amdgcn_exp2f(fmaf(st0[r], SCALE, -m_i));
      st1[r] = __builtin_amdgcn_exp2f(fmaf(st1[r], SCALE, -m_i));
      rs += st0[r] + st1[r];
    }
    rs += __shfl_xor(rs, 32);
    l_i += rs;
    // ---- P exchange + PV: per k-slot, build A-frag and MFMA immediately ----
#define PV_KS(KS, PVEC, RL)                                              \
    {                                                                    \
      unsigned int a0 = pkbf(PVEC[RL + 0], PVEC[RL + 1]);                \
      unsigned int a1 = pkbf(PVEC[RL + 2], PVEC[RL + 3]);                \
      unsigned int b0 = pkbf(PVEC[RL + 4], PVEC[RL + 5]);                \
      unsigned int b1 = pkbf(PVEC[RL + 6], PVEC[RL + 7]);                \
      unsigned int s0 = hi ? a0 : b0, s1 = hi ? a1 : b1;                 \
      unsigned int r0 = __shfl_xor(s0, 32), r1 = __shfl_xor(s1, 32);     \
      u32x4 pw;                                                          \
      pw[0] = hi ? r0 : a0; pw[1] = hi ? r1 : a1;                        \
      pw[2] = hi ? b0 : r0; pw[3] = hi ? b1 : r1;                        \
      bf16x8 paf = __builtin_bit_cast(bf16x8, pw);                       \
      bf16x8 v0f = *(const bf16x8*)&Vt[cur][q_l][(KS)*16 + hi * 8];      \
      bf16x8 v1f = *(const bf16x8*)&Vt[cur][32 + q_l][(KS)*16 + hi * 8]; \
      o0 = MFMA32(v0f, paf, o0);                                         \
      o1 = MFMA32(v1f, paf, o1);                                         \
    }
    PV_KS(0, st0, 0)
    PV_KS(1, st0, 8)
    PV_KS(2, st1, 0)
    PV_KS(3, st1, 8)
#undef PV_KS
    // ---- land next V tile (transpose-write into the other buffer) ----
#pragma unroll
    for (int e = 0; e < 8; ++e) {
      Vt[nxt][vds + e][vkey] = v0n[e];
      Vt[nxt][vds + 8 + e][vkey] = v1n[e];
    }
    __syncthreads();  // staged K (vmcnt) + Vt writes visible; cur reads done
  }
  // ---- epilogue: O[q][d], q = q_l lane-local; d = dt*32 + 8g + 4hi + j ----
  const float inv = 1.f / l_i;
  const size_t row = (size_t)(b * SL + qt * 128 + wq + q_l) * CD + h * HD;
#pragma unroll
  for (int g = 0; g < 4; ++g) {
    uint2 w0, w1;
    w0.x = pkbf(o0[4 * g + 0] * inv, o0[4 * g + 1] * inv);
    w0.y = pkbf(o0[4 * g + 2] * inv, o0[4 * g + 3] * inv);
    *(uint2*)&ctx[row + 8 * g + 4 * hi] = w0;
    w1.x = pkbf(o1[4 * g + 0] * inv, o1[4 * g + 1] * inv);
    w1.y = pkbf(o1[4 * g + 2] * inv, o1[4 * g + 3] * inv);
    *(uint2*)&ctx[row + 32 + 8 * g + 4 * hi] = w1;
  }
#undef STAGE_K
}

extern "C" void kernel_launch(void* const* d_in, const int* in_sizes, int n_in,
                              void* d_out, int out_size, void* d_ws, size_t ws_size,
                              hipStream_t stream) {
  const float* x     = (const float*)d_in[0];  // (8,32,32,768) fp32
  const float* w_qkv = (const float*)d_in[1];  // (2304,768) fp32
  const float* qg    = (const float*)d_in[2];  // (64,) fp32
  const float* kg    = (const float*)d_in[3];  // (64,) fp32
  const float* w_out = (const float*)d_in[4];  // (768,768) fp32
  // d_out: fp32.

  // ws: xb | wqb | wob | qkv | ctx (bf16) | rtab (float2, 256KB)
  unsigned short* xb  = (unsigned short*)d_ws;
  unsigned short* wqb = xb + (size_t)NB * SL * CD;
  unsigned short* wob = wqb + (size_t)QKVD * CD;
  unsigned short* qkv = wob + (size_t)CD * CD;
  unsigned short* ctx = qkv + (size_t)NB * SL * QKVD;
  float2* rtab = (float2*)(ctx + (size_t)NB * SL * CD);

  const int M = NB * SL;  // 8192
  dim3 blk(256);
  // 0) fused converts + RoPE table (one launch; total items /256 = 8576 exact)
  prep_kernel<<<dim3((PN0 + PN1 + PN2 + PN3) / 256), blk, 0, stream>>>(
      (const float4*)x, (const float4*)w_qkv, (const float4*)w_out,
      (ushort4*)xb, (ushort4*)wqb, (ushort4*)wob, rtab);
  // 1) qkv = x @ w_qkv^T with fused RMSNorm+RoPE on q,k head-columns
  gemm_mfma<2><<<dim3(QKVD / 128, M / 128), blk, 0, stream>>>(
      xb, wqb, qkv, M, QKVD, CD, qg, kg, rtab);
  // 2) attention -> ctx (bf16)
  attn_mfma<<<dim3(SL / 128, NHH, NB), blk, 0, stream>>>(qkv, ctx);
  // 3) out = ctx @ w_out^T  (fp32 out)
  gemm_mfma<1><<<dim3(CD / 128, M / 128), blk, 0, stream>>>(
      ctx, wob, d_out, M, CD, CD, nullptr, nullptr, nullptr);
}

// Round 12
// 212.530 us; speedup vs baseline: 1.6146x; 1.0005x over previous
//
#include <hip/hip_runtime.h>
#include <math.h>

// Problem: B=8, L=1024, C=768, nH=12, hd=64, qkv dim 2304. fp32 in, fp32 out.
#define NB 8
#define SL 1024
#define CD 768
#define NHH 12
#define HD 64
#define QKVD 2304

typedef __attribute__((ext_vector_type(8))) __bf16 bf16x8;
typedef __attribute__((ext_vector_type(8))) unsigned short u16x8;
typedef __attribute__((ext_vector_type(4))) float f32x4;
typedef __attribute__((ext_vector_type(16))) float f32x16;
typedef __attribute__((ext_vector_type(4))) unsigned int u32x4;
#define MFMA16(a, b, c) __builtin_amdgcn_mfma_f32_16x16x32_bf16(a, b, c, 0, 0, 0)
#define MFMA32(a, b, c) __builtin_amdgcn_mfma_f32_32x32x16_bf16(a, b, c, 0, 0, 0)

__host__ __device__ __forceinline__ float bf2f(unsigned short u) {
  union { unsigned int i; float f; } v; v.i = ((unsigned int)u) << 16; return v.f;
}
__host__ __device__ __forceinline__ unsigned short f2bf(float f) {
  union { float ff; unsigned int i; } v; v.ff = f;
  unsigned int x = v.i;
  x += 0x7FFFu + ((x >> 16) & 1u);  // RNE
  return (unsigned short)(x >> 16);
}
// pack two floats to bf16 pair (hw cvt, RNE) -> u32 (lo = first)
__device__ __forceinline__ unsigned int pkbf(float a, float b) {
  unsigned short ua = __builtin_bit_cast(unsigned short, (__bf16)a);
  unsigned short ub = __builtin_bit_cast(unsigned short, (__bf16)b);
  return ((unsigned int)ub << 16) | ua;
}

// async global->LDS, 16B per lane. LDS dest must be linear in lane order.
__device__ __forceinline__ void gload_lds16(const void* g, void* l) {
  __builtin_amdgcn_global_load_lds(
      (const __attribute__((address_space(1))) unsigned int*)g,
      (__attribute__((address_space(3))) unsigned int*)l, 16, 0, 0);
}

// Fused prep: 3x fp32->bf16 convert + RoPE cos/sin table, ONE launch
// (launch gaps ~8us each dominate these tiny kernels).
#define PN0 (NB * SL * CD / 4)   // x float4s
#define PN1 (QKVD * CD / 4)      // w_qkv
#define PN2 (CD * CD / 4)        // w_out
#define PN3 (SL * 32)            // rope table entries
__global__ __launch_bounds__(256) void prep_kernel(
    const float4* __restrict__ x, const float4* __restrict__ wq,
    const float4* __restrict__ wo, ushort4* __restrict__ xb,
    ushort4* __restrict__ wqb, ushort4* __restrict__ wob,
    float2* __restrict__ rt)
{
  int i = blockIdx.x * 256 + threadIdx.x;
  if (i < PN0 + PN1 + PN2) {
    const float4* src; ushort4* dst; int k;
    if (i < PN0) { src = x; dst = xb; k = i; }
    else if (i < PN0 + PN1) { src = wq; dst = wqb; k = i - PN0; }
    else { src = wo; dst = wob; k = i - PN0 - PN1; }
    float4 v = src[k];
    ushort4 o;
    o.x = f2bf(v.x); o.y = f2bf(v.y); o.z = f2bf(v.z); o.w = f2bf(v.w);
    dst[k] = o;
  } else {
    int k = i - PN0 - PN1 - PN2;  // < PN3 by grid sizing
    int l = k >> 5, j = k & 31;
    float ang = (float)l * exp2f((float)j * (-13.287712379549449f / 32.0f));
    float sn, cs;
    sincosf(ang, &sn, &cs);
    rt[k] = make_float2(cs, sn);
  }
}

// C[M,N] = A[M,K] @ B[N,K]^T, A,B bf16.
// MODE 0: bf16 out. MODE 1: fp32 out. MODE 2: bf16 out with fused
// RMSNorm(hd=64)+RoPE (table-driven) on q/k head-columns.
// 2-phase double-buffered gload_lds staging + 16B-chunk src-swizzle
// g(row)=(row>>1)&3 (LDS reads 2 lanes/bank = free) + XCD block swizzle.
// NOTE: the s_setprio(1)/(0) pair around the MFMA block is LOAD-BEARING in
// this build: removing it (r8-r11) correlated with absmax 1.7-1.9e-02
// miscompares on two different attn implementations; restoring it (exact r7
// source) is this round's single variable.
template <int MODE>
__global__ __launch_bounds__(256) void gemm_mfma(
    const unsigned short* __restrict__ A, const unsigned short* __restrict__ B,
    void* __restrict__ Cv, int M, int N, int K,
    const float* __restrict__ qg, const float* __restrict__ kg,
    const float2* __restrict__ rt)
{
  __shared__ alignas(16) unsigned short AsL[2][128 * 32];
  __shared__ alignas(16) unsigned short BsL[2][128 * 32];
  // XCD swizzle (bijective: nwg % 8 == 0 for both gemm grids)
  const int bid = (int)(blockIdx.x + gridDim.x * blockIdx.y);
  const int cpx = (int)(gridDim.x * gridDim.y) >> 3;
  const int nb = (bid & 7) * cpx + (bid >> 3);
  const int bx = nb % (int)gridDim.x, by = nb / (int)gridDim.x;
  const int m0 = by * 128, n0 = bx * 128;
  const int t = threadIdx.x;
  const int wave = t >> 6, lane = t & 63;
  const int wm = (wave >> 1) * 64, wn = (wave & 1) * 64;
  const int lm = lane & 15, quad = lane >> 4;
  const int rq = (quad ^ ((lm >> 1) & 3)) * 8;  // swizzled read chunk offset
  f32x4 acc[4][4];
#pragma unroll
  for (int i = 0; i < 4; ++i)
#pragma unroll
    for (int j = 0; j < 4; ++j)
#pragma unroll
      for (int r = 0; r < 4; ++r) acc[i][j][r] = 0.f;

  // staging: thread t covers row sr (of 64-row half), 16B chunk kc4;
  // source pre-swizzled: LDS[r][c] = G[r][c ^ ((r>>1)&3)].
  const int sr = t >> 2, kc4 = t & 3;
  const int scs = (kc4 ^ ((sr >> 1) & 3)) * 8;
  const unsigned short* ag = A + (size_t)(m0 + sr) * K + scs;
  const unsigned short* bg = B + (size_t)(n0 + sr) * K + scs;
#define STAGE_G(K0, BUF)                                          \
  {                                                               \
    gload_lds16(ag + (K0), &AsL[BUF][t * 8]);                     \
    gload_lds16(ag + (size_t)64 * K + (K0), &AsL[BUF][2048 + t * 8]); \
    gload_lds16(bg + (K0), &BsL[BUF][t * 8]);                     \
    gload_lds16(bg + (size_t)64 * K + (K0), &BsL[BUF][2048 + t * 8]); \
  }

  STAGE_G(0, 0);
  __syncthreads();
  int cur = 0;
  for (int k0 = 0; k0 < K; k0 += 32) {
    if (k0 + 32 < K) STAGE_G(k0 + 32, cur ^ 1);  // issue next (hides latency)
    bf16x8 af[4], bfr[4];
#pragma unroll
    for (int i = 0; i < 4; ++i)
      af[i] = *(const bf16x8*)&AsL[cur][(wm + i * 16 + lm) * 32 + rq];
#pragma unroll
    for (int j = 0; j < 4; ++j)
      bfr[j] = *(const bf16x8*)&BsL[cur][(wn + j * 16 + lm) * 32 + rq];
    __builtin_amdgcn_s_setprio(1);
#pragma unroll
    for (int i = 0; i < 4; ++i)
#pragma unroll
      for (int j = 0; j < 4; ++j)
        acc[i][j] = MFMA16(af[i], bfr[j], acc[i][j]);
    __builtin_amdgcn_s_setprio(0);
    __syncthreads();  // drains vmcnt (next-tile loads had MFMA time to land)
    cur ^= 1;
  }
#undef STAGE_G

  // ---- fused RMSNorm + RoPE epilogue (MODE 2, q/k planes only) ----
  if (MODE == 2 && (n0 + wn) < 2 * CD) {
    const float* gam = ((n0 + wn) >= CD) ? kg : qg;
    float g4[4];
#pragma unroll
    for (int j = 0; j < 4; ++j) g4[j] = gam[j * 16 + lm];
    unsigned short* Cs = (unsigned short*)Cv;
#pragma unroll
    for (int i = 0; i < 4; ++i) {
      const int row = m0 + wm + i * 16 + quad * 4;
#pragma unroll
      for (int r = 0; r < 4; ++r) {
        float v0 = acc[i][0][r], v1 = acc[i][1][r];
        float v2 = acc[i][2][r], v3 = acc[i][3][r];
        float ssq = v0 * v0 + v1 * v1 + v2 * v2 + v3 * v3;
#pragma unroll
        for (int off = 8; off; off >>= 1) ssq += __shfl_xor(ssq, off);
        const float sc2 = rsqrtf(ssq * (1.0f / 64.0f) + 1e-6f);
        v0 *= sc2 * g4[0]; v1 *= sc2 * g4[1];
        v2 *= sc2 * g4[2]; v3 *= sc2 * g4[3];
        const int l = (row + r) & (SL - 1);
        const float2 t0 = rt[l * 32 + lm];        // {cos,sin} dd=lm
        const float2 t1 = rt[l * 32 + 16 + lm];   // {cos,sin} dd=16+lm
        const size_t base = (size_t)(row + r) * N + n0 + wn + lm;
        Cs[base +  0] = f2bf(v0 * t0.x - v2 * t0.y);   // dd = lm
        Cs[base + 16] = f2bf(v1 * t1.x - v3 * t1.y);   // dd = 16+lm
        Cs[base + 32] = f2bf(v0 * t0.y + v2 * t0.x);   // dd = 32+lm
        Cs[base + 48] = f2bf(v1 * t1.y + v3 * t1.x);   // dd = 48+lm
      }
    }
    return;
  }

#pragma unroll
  for (int i = 0; i < 4; ++i) {
    const int row = m0 + wm + i * 16 + quad * 4;
#pragma unroll
    for (int r = 0; r < 4; ++r) {
      const size_t base = (size_t)(row + r) * N + n0 + wn + lm;
#pragma unroll
      for (int j = 0; j < 4; ++j) {
        if (MODE == 1) ((float*)Cv)[base + j * 16] = acc[i][j][r];
        else ((unsigned short*)Cv)[base + j * 16] = f2bf(acc[i][j][r]);
      }
    }
  }
}

// MFMA flash attention, v7 (exact r7 source, both setprio pairs as passed):
// swapped-operand 32x32, in-register log2 softmax with defer-max, K via
// global_load_lds w16 (src-swizzled linear LDS), K/V double-buffered, one
// barrier/iter, XCD swizzle.
__global__ __launch_bounds__(256) void attn_mfma(
    const unsigned short* __restrict__ qkv, unsigned short* __restrict__ ctx)
{
  __shared__ alignas(16) unsigned short KsL[2][64 * 64];  // linear, src-swizzled
  __shared__ alignas(16) unsigned short Vt[2][64][76];    // [d][key], stride 152B
  // XCD swizzle: grid (8,12,8) x-major linear; 768 = 8 XCD * 96.
  const int bid = (int)(blockIdx.x + 8 * (blockIdx.y + 12 * blockIdx.z));
  const int nb = (bid & 7) * 96 + (bid >> 3);  // bijective
  const int qt = nb & 7;
  const int h = (nb >> 3) % 12;
  const int b = nb / 96;
  const int t = threadIdx.x, wave = t >> 6, lane = t & 63;
  const int q_l = lane & 31, hi = lane >> 5;
  const int wq = wave * 32;                      // wave's q offset in 128-tile
  const int vkey = t & 63, vds = (t >> 6) * 16;  // V staging assignment
  const int kr = t >> 3, kc = t & 7;             // K staging: row, 16B chunk
  const float SCALE = 0.125f * 1.44269504088896340736f;  // 1/sqrt(64) * log2(e)

  const unsigned short* base_k = qkv + (size_t)b * SL * QKVD + (NHH * HD) + h * HD;
  const unsigned short* base_v = qkv + (size_t)b * SL * QKVD + 2 * (NHH * HD) + h * HD;

  // Q fragments (B-operand): Q[q = qt*128+wq+q_l][d = ds*16 + hi*8 + e]
  bf16x8 qf[4];
  {
    const unsigned short* qp =
        qkv + (((size_t)(b * SL + qt * 128 + wq + q_l) * 3 + 0) * NHH + h) * HD + hi * 8;
#pragma unroll
    for (int ds = 0; ds < 4; ++ds) qf[ds] = *(const bf16x8*)(qp + ds * 16);
  }
  f32x16 o0, o1;  // O^T[d = dt*32 + crow(r,hi)][q = q_l]
#pragma unroll
  for (int r = 0; r < 16; ++r) { o0[r] = 0.f; o1[r] = 0.f; }
  float m_i = -INFINITY, l_i = 0.f;  // log2-scaled units

  const int ksw = (kc ^ (kr & 7)) * 8;  // swizzled chunk, ushort offset
#define STAGE_K(KT, BUF)                                                      \
  {                                                                           \
    const unsigned short* k0p = base_k + (size_t)((KT)*64 + kr) * QKVD + ksw; \
    gload_lds16(k0p, &KsL[BUF][t * 8]);                                       \
    const unsigned short* k1p =                                               \
        base_k + (size_t)((KT)*64 + 32 + kr) * QKVD + ksw;                    \
    gload_lds16(k1p, &KsL[BUF][2048 + t * 8]);                                \
  }

  // prologue: stage tile 0 into buf 0
  STAGE_K(0, 0);
  {
    const unsigned short* vp = base_v + (size_t)vkey * QKVD + vds;
    u16x8 v0 = *(const u16x8*)(vp);
    u16x8 v1 = *(const u16x8*)(vp + 8);
#pragma unroll
    for (int e = 0; e < 8; ++e) {
      Vt[0][vds + e][vkey] = v0[e];
      Vt[0][vds + 8 + e][vkey] = v1[e];
    }
  }
  __syncthreads();

  for (int kt = 0; kt < 16; ++kt) {
    const int cur = kt & 1, nxt = cur ^ 1;
    const int ktn = (kt + 1) & 15;  // last iter re-stages tile 0 (unused)
    // ---- issue next tile's staging first (latency hides under compute) ----
    STAGE_K(ktn, nxt);
    const unsigned short* vp = base_v + (size_t)(ktn * 64 + vkey) * QKVD + vds;
    u16x8 v0n = *(const u16x8*)(vp);
    u16x8 v1n = *(const u16x8*)(vp + 8);
    // ---- S^T = K Q^T : st0 = keys 0-31, st1 = keys 32-63 ----
    const unsigned short* Kb = KsL[cur];
    f32x16 st0, st1;
#pragma unroll
    for (int r = 0; r < 16; ++r) { st0[r] = 0.f; st1[r] = 0.f; }
    __builtin_amdgcn_s_setprio(1);
#pragma unroll
    for (int ds = 0; ds < 4; ++ds) {
      const int c = 2 * ds + hi;  // 16B chunk covering d = ds*16 + hi*8
      bf16x8 k0 = *(const bf16x8*)&Kb[q_l * 64 + ((c ^ (q_l & 7)) * 8)];
      bf16x8 k1 = *(const bf16x8*)&Kb[(32 + q_l) * 64 + ((c ^ (q_l & 7)) * 8)];
      st0 = MFMA32(k0, qf[ds], st0);
      st1 = MFMA32(k1, qf[ds], st1);
    }
    __builtin_amdgcn_s_setprio(0);
    // ---- online softmax, log2 domain, defer-max ----
    float t0 = fmaxf(st0[0], st1[0]), t1 = fmaxf(st0[1], st1[1]);
    float t2 = fmaxf(st0[2], st1[2]), t3 = fmaxf(st0[3], st1[3]);
#pragma unroll
    for (int r = 4; r < 16; r += 4) {
      t0 = fmaxf(t0, fmaxf(st0[r + 0], st1[r + 0]));
      t1 = fmaxf(t1, fmaxf(st0[r + 1], st1[r + 1]));
      t2 = fmaxf(t2, fmaxf(st0[r + 2], st1[r + 2]));
      t3 = fmaxf(t3, fmaxf(st0[r + 3], st1[r + 3]));
    }
    float tm = fmaxf(fmaxf(t0, t1), fmaxf(t2, t3)) * SCALE;
    tm = fmaxf(tm, __shfl_xor(tm, 32));  // full 64-key max for this q
    if (!__all(tm - m_i <= 8.0f)) {      // rescale only on real max growth
      const float mn = fmaxf(m_i, tm);
      const float al = __builtin_amdgcn_exp2f(m_i - mn);
      m_i = mn;
      l_i *= al;
#pragma unroll
      for (int r = 0; r < 16; ++r) { o0[r] *= al; o1[r] *= al; }
    }
    float rs = 0.f;
#pragma unroll
    for (int r = 0; r < 16; ++r) {
      st0[r] = __builtin_amdgcn_exp2f(fmaf(st0[r], SCALE, -m_i));
      st1[r] = __builtin_amdgcn_exp2f(fmaf(st1[r], SCALE, -m_i));
      rs += st0[r] + st1[r];
    }
    rs += __shfl_xor(rs, 32);
    l_i += rs;
    // ---- P exchange + PV: per k-slot, build A-frag and MFMA immediately ----
#define PV_KS(KS, PVEC, RL)                                              \
    {                                                                    \
      unsigned int a0 = pkbf(PVEC[RL + 0], PVEC[RL + 1]);                \
      unsigned int a1 = pkbf(PVEC[RL + 2], PVEC[RL + 3]);                \
      unsigned int b0 = pkbf(PVEC[RL + 4], PVEC[RL + 5]);                \
      unsigned int b1 = pkbf(PVEC[RL + 6], PVEC[RL + 7]);                \
      unsigned int s0 = hi ? a0 : b0, s1 = hi ? a1 : b1;                 \
      unsigned int r0 = __shfl_xor(s0, 32), r1 = __shfl_xor(s1, 32);     \
      u32x4 pw;                                                          \
      pw[0] = hi ? r0 : a0; pw[1] = hi ? r1 : a1;                        \
      pw[2] = hi ? b0 : r0; pw[3] = hi ? b1 : r1;                        \
      bf16x8 paf = __builtin_bit_cast(bf16x8, pw);                       \
      bf16x8 v0f = *(const bf16x8*)&Vt[cur][q_l][(KS)*16 + hi * 8];      \
      bf16x8 v1f = *(const bf16x8*)&Vt[cur][32 + q_l][(KS)*16 + hi * 8]; \
      o0 = MFMA32(v0f, paf, o0);                                         \
      o1 = MFMA32(v1f, paf, o1);                                         \
    }
    PV_KS(0, st0, 0)
    PV_KS(1, st0, 8)
    PV_KS(2, st1, 0)
    PV_KS(3, st1, 8)
#undef PV_KS
    // ---- land next V tile (transpose-write into the other buffer) ----
#pragma unroll
    for (int e = 0; e < 8; ++e) {
      Vt[nxt][vds + e][vkey] = v0n[e];
      Vt[nxt][vds + 8 + e][vkey] = v1n[e];
    }
    __syncthreads();  // staged K (vmcnt) + Vt writes visible; cur reads done
  }
  // ---- epilogue: O[q][d], q = q_l lane-local; d = dt*32 + 8g + 4hi + j ----
  const float inv = 1.f / l_i;
  const size_t row = (size_t)(b * SL + qt * 128 + wq + q_l) * CD + h * HD;
#pragma unroll
  for (int g = 0; g < 4; ++g) {
    uint2 w0, w1;
    w0.x = pkbf(o0[4 * g + 0] * inv, o0[4 * g + 1] * inv);
    w0.y = pkbf(o0[4 * g + 2] * inv, o0[4 * g + 3] * inv);
    *(uint2*)&ctx[row + 8 * g + 4 * hi] = w0;
    w1.x = pkbf(o1[4 * g + 0] * inv, o1[4 * g + 1] * inv);
    w1.y = pkbf(o1[4 * g + 2] * inv, o1[4 * g + 3] * inv);
    *(uint2*)&ctx[row + 32 + 8 * g + 4 * hi] = w1;
  }
#undef STAGE_K
}

extern "C" void kernel_launch(void* const* d_in, const int* in_sizes, int n_in,
                              void* d_out, int out_size, void* d_ws, size_t ws_size,
                              hipStream_t stream) {
  const float* x     = (const float*)d_in[0];  // (8,32,32,768) fp32
  const float* w_qkv = (const float*)d_in[1];  // (2304,768) fp32
  const float* qg    = (const float*)d_in[2];  // (64,) fp32
  const float* kg    = (const float*)d_in[3];  // (64,) fp32
  const float* w_out = (const float*)d_in[4];  // (768,768) fp32
  // d_out: fp32.

  // ws: xb | wqb | wob | qkv | ctx (bf16) | rtab (float2, 256KB)
  unsigned short* xb  = (unsigned short*)d_ws;
  unsigned short* wqb = xb + (size_t)NB * SL * CD;
  unsigned short* wob = wqb + (size_t)QKVD * CD;
  unsigned short* qkv = wob + (size_t)CD * CD;
  unsigned short* ctx = qkv + (size_t)NB * SL * QKVD;
  float2* rtab = (float2*)(ctx + (size_t)NB * SL * CD);

  const int M = NB * SL;  // 8192
  dim3 blk(256);
  // 0) fused converts + RoPE table (one launch; total items /256 = 8576 exact)
  prep_kernel<<<dim3((PN0 + PN1 + PN2 + PN3) / 256), blk, 0, stream>>>(
      (const float4*)x, (const float4*)w_qkv, (const float4*)w_out,
      (ushort4*)xb, (ushort4*)wqb, (ushort4*)wob, rtab);
  // 1) qkv = x @ w_qkv^T with fused RMSNorm+RoPE on q,k head-columns
  gemm_mfma<2><<<dim3(QKVD / 128, M / 128), blk, 0, stream>>>(
      xb, wqb, qkv, M, QKVD, CD, qg, kg, rtab);
  // 2) attention -> ctx (bf16)
  attn_mfma<<<dim3(SL / 128, NHH, NB), blk, 0, stream>>>(qkv, ctx);
  // 3) out = ctx @ w_out^T  (fp32 out)
  gemm_mfma<1><<<dim3(CD / 128, M / 128), blk, 0, stream>>>(
      ctx, wob, d_out, M, CD, CD, nullptr, nullptr, nullptr);
}